// Round 4
// baseline (822.753 us; speedup 1.0000x reference)
//
#include <hip/hip_runtime.h>
#include <math.h>

#define B_   8
#define Hs   56
#define Ws   56
#define Cc   768
#define NHh  12
#define HDd  64
#define Nt   3137
#define HW_  3136
#define C3   2304
#define SCALE 0.125f
#define Mrows (B_ * Nt)        // 25096
#define Mpad  (99 * 256)       // 25344 (multiple of 256 and 128)

typedef _Float16 half8  __attribute__((ext_vector_type(8)));
typedef _Float16 half4  __attribute__((ext_vector_type(4)));
typedef _Float16 half2_ __attribute__((ext_vector_type(2)));
typedef float floatx4 __attribute__((ext_vector_type(4)));

#define WAITV(N) asm volatile("s_waitcnt vmcnt(" #N ")" ::: "memory")
#define WAITL    asm volatile("s_waitcnt lgkmcnt(0)" ::: "memory")

__device__ __forceinline__ void barrier_mem() {
    asm volatile("" ::: "memory");
    __builtin_amdgcn_s_barrier();
    asm volatile("" ::: "memory");
}

__device__ inline float fdot2f(half2_ a, half2_ b, float c) {
#if __has_builtin(__builtin_amdgcn_fdot2)
    return __builtin_amdgcn_fdot2(a, b, c, false);
#else
    return fmaf((float)a.x, (float)b.x, fmaf((float)a.y, (float)b.y, c));
#endif
}

__device__ __forceinline__ void gload_lds16(const _Float16* g, _Float16* l) {
    __builtin_amdgcn_global_load_lds(
        (const __attribute__((address_space(1))) void*)g,
        (__attribute__((address_space(3))) void*)l, 16, 0, 0);
}

// ---------------- scratch (__device__ globals) -----------------------------
__device__ _Float16 g_qkvh[(size_t)Mrows * C3];          // fp16 qkv (115 MB)
__device__ float    g_Ocol[(size_t)B_ * NHh * HW_ * HDd];
__device__ float    g_mcol[(size_t)B_ * NHh * HW_];
__device__ float    g_lcol[(size_t)B_ * NHh * HW_];
__device__ _Float16 g_xh[(size_t)Mpad * Cc];
__device__ _Float16 g_attH[(size_t)Mpad * Cc];
__device__ _Float16 g_WqkvT[(size_t)C3 * Cc];
__device__ _Float16 g_WprojT[(size_t)Cc * Cc];
__device__ float    g_clsP[(size_t)B_ * NHh * 4 * 66];   // per-partial: m,l,O[64]

// ---------------- fp32 -> fp16 convert -------------------------------------
__global__ __launch_bounds__(256) void cvt_f16(
    const float* __restrict__ in, _Float16* __restrict__ out, int n4)
{
    for (int i = blockIdx.x * 256 + threadIdx.x; i < n4; i += gridDim.x * 256) {
        float4 v = ((const float4*)in)[i];
        half4 h = { (_Float16)v.x, (_Float16)v.y, (_Float16)v.z, (_Float16)v.w };
        ((half4*)out)[i] = h;
    }
}

// ---------------- fp32 [R][Cq] -> fp16 transposed [Cq][R] ------------------
__global__ __launch_bounds__(256) void transpose_f16(
    const float* __restrict__ in, _Float16* __restrict__ out, int R, int Cq)
{
    __shared__ float t[32][33];
    const int c0 = blockIdx.x * 32, r0 = blockIdx.y * 32;
    const int tx = threadIdx.x & 31, ty = threadIdx.x >> 5;
#pragma unroll
    for (int i = 0; i < 32; i += 8)
        t[ty + i][tx] = in[(size_t)(r0 + ty + i) * Cq + c0 + tx];
    __syncthreads();
#pragma unroll
    for (int i = 0; i < 32; i += 8)
        out[(size_t)(c0 + ty + i) * R + r0 + tx] = (_Float16)t[tx][ty + i];
}

// ---------------------------------------------------------------------------
// fp16 MFMA GEMM: C[M,Nd] = A[Mpad,K] @ Bt[Nd,K]^T (+bias).
// 8-phase schedule (T3+T4+T5), BMx256 tile, BK=64, 512 thr (8 waves 2Mx4N).
// Two LDS dbufs; per K-tile 4 phases, counted vmcnt once per tile (never 0
// in steady state). Epilogue: LDS bounce -> coalesced 16B/lane stores.
// ---------------------------------------------------------------------------
template <typename OutT, int BM>
__global__ __launch_bounds__(512, 2) void gemm_f16(
    const _Float16* __restrict__ A, const _Float16* __restrict__ Bt,
    const float* __restrict__ bias, OutT* __restrict__ Cm,
    int M, int Nd, int K)
{
    constexpr int MI   = BM / 32;        // acc rows per wave (8 or 4)
    constexpr int MIH  = MI / 2;
    constexpr int LA   = BM / 128;       // loads/thread per A half-tile (2 or 1)
    constexpr int ASZh = BM * 64;        // halfs per A K-tile buffer
    constexpr int BSZh = 256 * 64;       // halfs per B K-tile buffer
    constexpr size_t MAINB = (size_t)2 * (ASZh + BSZh) * 2;
    constexpr size_t EPIB  = sizeof(OutT) == 2 ? (size_t)BM * 280 * 2
                                               : (size_t)BM * 140 * 4;
    constexpr size_t SMEMB = MAINB > EPIB ? MAINB : EPIB;
    __shared__ __align__(16) char smem[SMEMB];

    const int tid = threadIdx.x;
    const int wave = tid >> 6, lane = tid & 63;
    const int wm = wave & 1, wn = wave >> 1;

    // panel swizzle: 16 row-blocks per panel, col-major within panel
    const int bid = blockIdx.y * gridDim.x + blockIdx.x;
    const int perPanel = gridDim.x * 16;
    const int panel = bid / perPanel;
    const int rowsIn = min(16, (int)gridDim.y - panel * 16);
    const int rem = bid - panel * perPanel;
    const int by = panel * 16 + rem % rowsIn;
    const int bx = rem / rowsIn;
    const int mBase = by * BM, nBase = bx * 256;

    const int rU  = ((tid >> 7) << 4) + (tid & 15);
    const int kcU = (tid >> 4) & 7;

    auto stageHalf = [&](int kt, int h) {
        _Float16* arena = (_Float16*)smem + (size_t)(kt & 1) * (ASZh + BSZh);
        if (h < 2) {
            _Float16* ldsA = arena + h * (ASZh / 2) + tid * 8;
            const _Float16* g = A + (size_t)(mBase + h * (BM / 2) + rU) * K
                                  + kt * 64 + kcU * 8;
#pragma unroll
            for (int j = 0; j < LA; ++j)
                gload_lds16(g + (size_t)j * 64 * K, ldsA + j * 4096);
        } else {
            const int hh = h - 2;
            _Float16* ldsB = arena + ASZh + hh * (BSZh / 2) + tid * 8;
            const _Float16* g = Bt + (size_t)(nBase + hh * 128 + rU) * K
                                   + kt * 64 + kcU * 8;
#pragma unroll
            for (int j = 0; j < 2; ++j)
                gload_lds16(g + (size_t)j * 64 * K, ldsB + j * 4096);
        }
    };

    const int fo = (lane >> 4) * 128 + (lane & 15) * 8;

    floatx4 acc[MI][4] = {};
    half8 a[MIH], b[4];

    const int NT = K >> 6;               // 12 K-tiles of 64
    stageHalf(0, 0); stageHalf(0, 1); stageHalf(0, 2); stageHalf(0, 3);

    for (int t = 0; t < NT; ++t) {
        const _Float16* aA = (const _Float16*)smem
                             + (size_t)(t & 1) * (ASZh + BSZh);
        const _Float16* aB = aA + ASZh;
        const bool st = (t + 1 < NT);

        // ---- q0: kk=0, mi-lo ----
        if (st) stageHalf(t + 1, 0);
        if (!st) { WAITV(0); }
        else if constexpr (LA == 2) { WAITV(2); }
        else { WAITV(1); }
        barrier_mem();
#pragma unroll
        for (int ni = 0; ni < 4; ++ni)
            b[ni] = *(const half8*)&aB[(wn * 4 + ni) * 1024 + fo];
#pragma unroll
        for (int mi = 0; mi < MIH; ++mi)
            a[mi] = *(const half8*)&aA[(wm * MI + mi) * 1024 + fo];
        WAITL;
        __builtin_amdgcn_s_setprio(1);
#pragma unroll
        for (int mi = 0; mi < MIH; ++mi)
#pragma unroll
            for (int ni = 0; ni < 4; ++ni)
                acc[mi][ni] = __builtin_amdgcn_mfma_f32_16x16x32_f16(
                    b[ni], a[mi], acc[mi][ni], 0, 0, 0);
        __builtin_amdgcn_s_setprio(0);
        barrier_mem();

        // ---- q1: kk=0, mi-hi ----
        if (st) stageHalf(t + 1, 1);
#pragma unroll
        for (int mi = 0; mi < MIH; ++mi)
            a[mi] = *(const half8*)&aA[(wm * MI + MIH + mi) * 1024 + fo];
        WAITL;
        __builtin_amdgcn_s_setprio(1);
#pragma unroll
        for (int mi = 0; mi < MIH; ++mi)
#pragma unroll
            for (int ni = 0; ni < 4; ++ni)
                acc[MIH + mi][ni] = __builtin_amdgcn_mfma_f32_16x16x32_f16(
                    b[ni], a[mi], acc[MIH + mi][ni], 0, 0, 0);
        __builtin_amdgcn_s_setprio(0);
        barrier_mem();

        // ---- q2: kk=1, mi-lo ----
        if (st) stageHalf(t + 1, 2);
#pragma unroll
        for (int ni = 0; ni < 4; ++ni)
            b[ni] = *(const half8*)&aB[(wn * 4 + ni) * 1024 + 512 + fo];
#pragma unroll
        for (int mi = 0; mi < MIH; ++mi)
            a[mi] = *(const half8*)&aA[(wm * MI + mi) * 1024 + 512 + fo];
        WAITL;
        __builtin_amdgcn_s_setprio(1);
#pragma unroll
        for (int mi = 0; mi < MIH; ++mi)
#pragma unroll
            for (int ni = 0; ni < 4; ++ni)
                acc[mi][ni] = __builtin_amdgcn_mfma_f32_16x16x32_f16(
                    b[ni], a[mi], acc[mi][ni], 0, 0, 0);
        __builtin_amdgcn_s_setprio(0);
        barrier_mem();

        // ---- q3: kk=1, mi-hi ----
        if (st) stageHalf(t + 1, 3);
#pragma unroll
        for (int mi = 0; mi < MIH; ++mi)
            a[mi] = *(const half8*)&aA[(wm * MI + MIH + mi) * 1024 + 512 + fo];
        WAITL;
        __builtin_amdgcn_s_setprio(1);
#pragma unroll
        for (int mi = 0; mi < MIH; ++mi)
#pragma unroll
            for (int ni = 0; ni < 4; ++ni)
                acc[MIH + mi][ni] = __builtin_amdgcn_mfma_f32_16x16x32_f16(
                    b[ni], a[mi], acc[MIH + mi][ni], 0, 0, 0);
        __builtin_amdgcn_s_setprio(0);
        barrier_mem();     // end of tile: all reads of dbuf(t) drained
    }

    // -------- epilogue: LDS bounce --------
    const int mlBase = wm * (BM / 2) + (lane & 15);
    const int nlBase = wn * 64 + ((lane >> 4) << 2);

    if constexpr (sizeof(OutT) == 2) {
        _Float16* Ch = (_Float16*)smem;          // [BM][280] halfs
#pragma unroll
        for (int ni = 0; ni < 4; ++ni) {
            const int nl = nlBase + ni * 16;
#pragma unroll
            for (int mi = 0; mi < MI; ++mi) {
                const int ml = mlBase + mi * 16;
                floatx4 v = acc[mi][ni];
                half4 h = { (_Float16)v[0], (_Float16)v[1],
                            (_Float16)v[2], (_Float16)v[3] };
                *(half4*)&Ch[ml * 280 + nl] = h;
            }
        }
        barrier_mem();
#pragma unroll
        for (int i = 0; i < BM / 16; ++i) {
            const int f = i * 512 + tid;
            const int row = f >> 5, u = f & 31;
            const int gm = mBase + row;
            if (gm < M)
                *(half8*)&Cm[(size_t)gm * Nd + nBase + u * 8] =
                    *(const half8*)&Ch[row * 280 + u * 8];
        }
    } else {
        float* Cf = (float*)smem;                // [BM][140] floats
#pragma unroll
        for (int nh = 0; nh < 2; ++nh) {
            barrier_mem();                       // prev pass reads done
            if ((wn >> 1) == nh) {
#pragma unroll
                for (int ni = 0; ni < 4; ++ni) {
                    const int n0 = nBase + wn * 64 + ((lane >> 4) << 2) + ni * 16;
                    float4 bv = bias ? *(const float4*)&bias[n0]
                                     : make_float4(0.f, 0.f, 0.f, 0.f);
                    const int nl = (wn & 1) * 64 + ((lane >> 4) << 2) + ni * 16;
#pragma unroll
                    for (int mi = 0; mi < MI; ++mi) {
                        const int ml = mlBase + mi * 16;
                        floatx4 v = acc[mi][ni];
                        float4 o = make_float4(v[0] + bv.x, v[1] + bv.y,
                                               v[2] + bv.z, v[3] + bv.w);
                        *(float4*)&Cf[ml * 140 + nl] = o;
                    }
                }
            }
            barrier_mem();
#pragma unroll
            for (int i = 0; i < BM / 16; ++i) {
                const int f = i * 512 + tid;
                const int row = f >> 5, u = f & 31;
                const int gm = mBase + row;
                if (gm < M)
                    *(float4*)&Cm[(size_t)gm * Nd + nBase + nh * 128 + u * 4] =
                        *(const float4*)&Cf[row * 140 + u * 4];
            }
        }
    }
}

// ---------------------------------------------------------------------------
// Column attention partials: block (w,nh,b), 64 thr. R4: K AND V fp16 in LDS
// (14.6 KB -> 11 blocks/CU, was 7); chunk-8 deferred softmax rescale (one
// O-rescale per 8 keys; PV inner = pure fma_mix, no corr multiply).
// Online softmax, unnormalized partial out (fp32).
// ---------------------------------------------------------------------------
__global__ __launch_bounds__(64) void col_attn(
    const _Float16* __restrict__ qkvh, float* __restrict__ Ocol,
    float* __restrict__ mcol, float* __restrict__ lcol)
{
    const int w = blockIdx.x, nh = blockIdx.y, b = blockIdx.z;
    __shared__ __align__(16) _Float16 Kh[57 * HDd];
    __shared__ __align__(16) _Float16 Vh[57 * HDd];
    const int tid = threadIdx.x;

    for (int e = tid; e < 57 * 8; e += 64) {
        int j = e >> 3, c = e & 7;
        int n = (j == 0) ? 0 : ((j - 1) * Ws + w + 1);
        const _Float16* base = qkvh + (size_t)(b * Nt + n) * C3 + nh * HDd + c * 8;
        *(half8*)&Kh[j * HDd + c * 8] = *(const half8*)(base + Cc);
        *(half8*)&Vh[j * HDd + c * 8] = *(const half8*)(base + 2 * Cc);
    }
    __syncthreads();

    if (tid < Hs) {
        const int h = tid;
        const int n = h * Ws + w + 1;
        const _Float16* qp = qkvh + (size_t)(b * Nt + n) * C3 + nh * HDd;
        half8 q8[8];
#pragma unroll
        for (int c = 0; c < 8; ++c) q8[c] = ((const half8*)qp)[c];

        float m = -INFINITY, l = 0.f;
        float4 O4[16] = {};

        for (int c8 = 0; c8 < 7; ++c8) {           // keys 0..55 in chunks of 8
            float s[8];
#pragma unroll
            for (int jj = 0; jj < 8; ++jj) {
                const int j = c8 * 8 + jj;
                const half8* kp = (const half8*)&Kh[j * HDd];
                float s0 = 0.f, s1 = 0.f, s2 = 0.f, s3 = 0.f;
#pragma unroll
                for (int c = 0; c < 8; ++c) {
                    half8 kk = kp[c];
                    const half2_* k2 = (const half2_*)&kk;
                    const half2_* qq = (const half2_*)&q8[c];
                    s0 = fdot2f(qq[0], k2[0], s0);
                    s1 = fdot2f(qq[1], k2[1], s1);
                    s2 = fdot2f(qq[2], k2[2], s2);
                    s3 = fdot2f(qq[3], k2[3], s3);
                }
                s[jj] = ((s0 + s1) + (s2 + s3)) * SCALE;
            }
            float mx = s[0];
#pragma unroll
            for (int jj = 1; jj < 8; ++jj) mx = fmaxf(mx, s[jj]);
            const float mn = fmaxf(m, mx);
            const float corr = __expf(m - mn);
            l *= corr;
#pragma unroll
            for (int d4 = 0; d4 < 16; ++d4) {
                O4[d4].x *= corr; O4[d4].y *= corr;
                O4[d4].z *= corr; O4[d4].w *= corr;
            }
#pragma unroll
            for (int jj = 0; jj < 8; ++jj) {
                const int j = c8 * 8 + jj;
                const float p = __expf(s[jj] - mn);
                l += p;
                const half8* vp = (const half8*)&Vh[j * HDd];
#pragma unroll
                for (int d8 = 0; d8 < 8; ++d8) {
                    half8 vv = vp[d8];
                    float4* o0 = &O4[d8 * 2];
                    float4* o1 = &O4[d8 * 2 + 1];
                    o0->x = fmaf((float)vv[0], p, o0->x);
                    o0->y = fmaf((float)vv[1], p, o0->y);
                    o0->z = fmaf((float)vv[2], p, o0->z);
                    o0->w = fmaf((float)vv[3], p, o0->w);
                    o1->x = fmaf((float)vv[4], p, o1->x);
                    o1->y = fmaf((float)vv[5], p, o1->y);
                    o1->z = fmaf((float)vv[6], p, o1->z);
                    o1->w = fmaf((float)vv[7], p, o1->w);
                }
            }
            m = mn;
        }
        {   // tail key j=56
            const half8* kp = (const half8*)&Kh[56 * HDd];
            float s0 = 0.f, s1 = 0.f, s2 = 0.f, s3 = 0.f;
#pragma unroll
            for (int c = 0; c < 8; ++c) {
                half8 kk = kp[c];
                const half2_* k2 = (const half2_*)&kk;
                const half2_* qq = (const half2_*)&q8[c];
                s0 = fdot2f(qq[0], k2[0], s0);
                s1 = fdot2f(qq[1], k2[1], s1);
                s2 = fdot2f(qq[2], k2[2], s2);
                s3 = fdot2f(qq[3], k2[3], s3);
            }
            const float s = ((s0 + s1) + (s2 + s3)) * SCALE;
            const float mn = fmaxf(m, s);
            const float corr = __expf(m - mn);
            const float p = __expf(s - mn);
            l = l * corr + p;
            const half8* vp = (const half8*)&Vh[56 * HDd];
#pragma unroll
            for (int d8 = 0; d8 < 8; ++d8) {
                half8 vv = vp[d8];
                float4* o0 = &O4[d8 * 2];
                float4* o1 = &O4[d8 * 2 + 1];
                o0->x = fmaf((float)vv[0], p, o0->x * corr);
                o0->y = fmaf((float)vv[1], p, o0->y * corr);
                o0->z = fmaf((float)vv[2], p, o0->z * corr);
                o0->w = fmaf((float)vv[3], p, o0->w * corr);
                o1->x = fmaf((float)vv[4], p, o1->x * corr);
                o1->y = fmaf((float)vv[5], p, o1->y * corr);
                o1->z = fmaf((float)vv[6], p, o1->z * corr);
                o1->w = fmaf((float)vv[7], p, o1->w * corr);
            }
            m = mn;
        }
        const size_t qi = (size_t)((b * NHh + nh) * HW_ + h * Ws + w);
        mcol[qi] = m;
        lcol[qi] = l;
#pragma unroll
        for (int d4 = 0; d4 < 16; ++d4)
            *(float4*)&Ocol[qi * HDd + d4 * 4] = O4[d4];
    }
}

// ---------------------------------------------------------------------------
// Row attention + merge -> attH (fp16). Same R4 structure (fp16 V, chunk-8
// deferred rescale); j==w masked via s=-1e30 -> p=0 (replaces `continue`).
// ---------------------------------------------------------------------------
__global__ __launch_bounds__(64) void row_attn_merge(
    const _Float16* __restrict__ qkvh, const float* __restrict__ Ocol,
    const float* __restrict__ mcol, const float* __restrict__ lcol,
    _Float16* __restrict__ attH)
{
    const int h = blockIdx.x, nh = blockIdx.y, b = blockIdx.z;
    __shared__ __align__(16) _Float16 Kh[Ws * HDd];
    __shared__ __align__(16) _Float16 Vh[Ws * HDd];
    const int tid = threadIdx.x;

    for (int e = tid; e < Ws * 8; e += 64) {
        int j = e >> 3, c = e & 7;
        int n = h * Ws + j + 1;
        const _Float16* base = qkvh + (size_t)(b * Nt + n) * C3 + nh * HDd + c * 8;
        *(half8*)&Kh[j * HDd + c * 8] = *(const half8*)(base + Cc);
        *(half8*)&Vh[j * HDd + c * 8] = *(const half8*)(base + 2 * Cc);
    }
    __syncthreads();

    if (tid < Ws) {
        const int w = tid;
        const int n = h * Ws + w + 1;
        const _Float16* qp = qkvh + (size_t)(b * Nt + n) * C3 + nh * HDd;
        half8 q8[8];
#pragma unroll
        for (int c = 0; c < 8; ++c) q8[c] = ((const half8*)qp)[c];

        float m = -INFINITY, l = 0.f;
        float4 O4[16] = {};

        for (int c8 = 0; c8 < 7; ++c8) {           // keys 0..55
            float s[8];
#pragma unroll
            for (int jj = 0; jj < 8; ++jj) {
                const int j = c8 * 8 + jj;
                const half8* kp = (const half8*)&Kh[j * HDd];
                float s0 = 0.f, s1 = 0.f, s2 = 0.f, s3 = 0.f;
#pragma unroll
                for (int c = 0; c < 8; ++c) {
                    half8 kk = kp[c];
                    const half2_* k2 = (const half2_*)&kk;
                    const half2_* qq = (const half2_*)&q8[c];
                    s0 = fdot2f(qq[0], k2[0], s0);
                    s1 = fdot2f(qq[1], k2[1], s1);
                    s2 = fdot2f(qq[2], k2[2], s2);
                    s3 = fdot2f(qq[3], k2[3], s3);
                }
                float sv = ((s0 + s1) + (s2 + s3)) * SCALE;
                s[jj] = (j == w) ? -1e30f : sv;    // diagonal mask -> p = 0
            }
            float mx = s[0];
#pragma unroll
            for (int jj = 1; jj < 8; ++jj) mx = fmaxf(mx, s[jj]);
            const float mn = fmaxf(m, mx);
            const float corr = __expf(m - mn);
            l *= corr;
#pragma unroll
            for (int d4 = 0; d4 < 16; ++d4) {
                O4[d4].x *= corr; O4[d4].y *= corr;
                O4[d4].z *= corr; O4[d4].w *= corr;
            }
#pragma unroll
            for (int jj = 0; jj < 8; ++jj) {
                const int j = c8 * 8 + jj;
                const float p = __expf(s[jj] - mn);
                l += p;
                const half8* vp = (const half8*)&Vh[j * HDd];
#pragma unroll
                for (int d8 = 0; d8 < 8; ++d8) {
                    half8 vv = vp[d8];
                    float4* o0 = &O4[d8 * 2];
                    float4* o1 = &O4[d8 * 2 + 1];
                    o0->x = fmaf((float)vv[0], p, o0->x);
                    o0->y = fmaf((float)vv[1], p, o0->y);
                    o0->z = fmaf((float)vv[2], p, o0->z);
                    o0->w = fmaf((float)vv[3], p, o0->w);
                    o1->x = fmaf((float)vv[4], p, o1->x);
                    o1->y = fmaf((float)vv[5], p, o1->y);
                    o1->z = fmaf((float)vv[6], p, o1->z);
                    o1->w = fmaf((float)vv[7], p, o1->w);
                }
            }
            m = mn;
        }

        const size_t qi = (size_t)((b * NHh + nh) * HW_ + h * Ws + w);
        const float mc = mcol[qi], lc = lcol[qi];
        const float mn = fmaxf(mc, m);
        const float fc = __expf(mc - mn);
        const float fr = __expf(m - mn);
        const float inv = 1.f / (lc * fc + l * fr);
        _Float16* op = attH + (size_t)(b * Nt + n) * Cc + nh * HDd;
        const float* ocp = Ocol + qi * HDd;
#pragma unroll
        for (int d4 = 0; d4 < 16; ++d4) {
            float4 oc = *(const float4*)(ocp + d4 * 4);
            half4 r = { (_Float16)((oc.x * fc + O4[d4].x * fr) * inv),
                        (_Float16)((oc.y * fc + O4[d4].y * fr) * inv),
                        (_Float16)((oc.z * fc + O4[d4].z * fr) * inv),
                        (_Float16)((oc.w * fc + O4[d4].w * fr) * inv) };
            *(half4*)(op + d4 * 4) = r;
        }
    }
}

// ---------------------------------------------------------------------------
// Cls-token attention, 4-way key-split for occupancy. Partial (m,l,O) per
// (b,nh,s); merged by cls_merge.
// ---------------------------------------------------------------------------
__global__ __launch_bounds__(1024) void cls_part(
    const _Float16* __restrict__ qkvh, float* __restrict__ P)
{
    const int nh = blockIdx.x, b = blockIdx.y, sidx = blockIdx.z;
    const int j0 = sidx * 785, j1 = min(Nt, j0 + 785);
    const int tid = threadIdx.x;
    const int lane = tid & 63, wv = tid >> 6;

    const float qd = (float)qkvh[(size_t)(b * Nt) * C3 + nh * HDd + lane];
    float m = -INFINITY, l = 0.f, Od = 0.f;

    for (int j = j0 + wv; j < j1; j += 16) {
        const _Float16* base = qkvh + (size_t)(b * Nt + j) * C3 + nh * HDd;
        float prod = qd * (float)base[Cc + lane];
#pragma unroll
        for (int off = 32; off >= 1; off >>= 1)
            prod += __shfl_xor(prod, off, 64);
        float s = prod * SCALE;
        float mn = fmaxf(m, s);
        float corr = __expf(m - mn);
        float p = __expf(s - mn);
        l = l * corr + p;
        Od = fmaf(Od, corr, p * (float)base[2 * Cc + lane]);
        m = mn;
    }

    __shared__ float sm[16], sl[16], sO[16][64];
    if (lane == 0) { sm[wv] = m; sl[wv] = l; }
    sO[wv][lane] = Od;
    __syncthreads();

    if (tid < 64) {
        float M2 = sm[0];
#pragma unroll
        for (int i = 1; i < 16; ++i) M2 = fmaxf(M2, sm[i]);
        float L = 0.f, OO = 0.f;
#pragma unroll
        for (int i = 0; i < 16; ++i) {
            float f = __expf(sm[i] - M2);
            L += sl[i] * f;
            OO += sO[i][tid] * f;
        }
        float* pp = P + (size_t)((b * NHh + nh) * 4 + sidx) * 66;
        if (tid == 0) { pp[0] = M2; pp[1] = L; }
        pp[2 + tid] = OO;
    }
}

__global__ __launch_bounds__(64) void cls_merge(
    const float* __restrict__ P, _Float16* __restrict__ attH)
{
    const int nh = blockIdx.x, b = blockIdx.y;
    const int tid = threadIdx.x;
    const float* p0 = P + (size_t)(b * NHh + nh) * 4 * 66;
    float M2 = fmaxf(fmaxf(p0[0], p0[66]), fmaxf(p0[132], p0[198]));
    float L = 0.f, OO = 0.f;
#pragma unroll
    for (int i = 0; i < 4; ++i) {
        const float* pp = p0 + i * 66;
        float f = __expf(pp[0] - M2);
        L += pp[1] * f;
        OO += pp[2 + tid] * f;
    }
    attH[(size_t)(b * Nt) * Cc + nh * HDd + tid] = (_Float16)(OO / L);
}

// ---------------------------------------------------------------------------
extern "C" void kernel_launch(void* const* d_in, const int* in_sizes, int n_in,
                              void* d_out, int out_size, void* d_ws, size_t ws_size,
                              hipStream_t stream)
{
    const float* x     = (const float*)d_in[0];
    const float* Wqkv  = (const float*)d_in[1];
    const float* Wproj = (const float*)d_in[2];
    const float* bproj = (const float*)d_in[3];
    float* out = (float*)d_out;

    _Float16* qkvh;   hipGetSymbolAddress((void**)&qkvh,   HIP_SYMBOL(g_qkvh));
    float*    Ocol;   hipGetSymbolAddress((void**)&Ocol,   HIP_SYMBOL(g_Ocol));
    float*    mcol;   hipGetSymbolAddress((void**)&mcol,   HIP_SYMBOL(g_mcol));
    float*    lcol;   hipGetSymbolAddress((void**)&lcol,   HIP_SYMBOL(g_lcol));
    _Float16* xh;     hipGetSymbolAddress((void**)&xh,     HIP_SYMBOL(g_xh));
    _Float16* attH;   hipGetSymbolAddress((void**)&attH,   HIP_SYMBOL(g_attH));
    _Float16* WqkvT;  hipGetSymbolAddress((void**)&WqkvT,  HIP_SYMBOL(g_WqkvT));
    _Float16* WprojT; hipGetSymbolAddress((void**)&WprojT, HIP_SYMBOL(g_WprojT));
    float*    clsP;   hipGetSymbolAddress((void**)&clsP,   HIP_SYMBOL(g_clsP));

    // 0) prep
    cvt_f16<<<4096, 256, 0, stream>>>(x, xh, (Mrows * Cc) / 4);
    transpose_f16<<<dim3(C3 / 32, Cc / 32), 256, 0, stream>>>(Wqkv, WqkvT, Cc, C3);
    transpose_f16<<<dim3(Cc / 32, Cc / 32), 256, 0, stream>>>(Wproj, WprojT, Cc, Cc);

    // 1) qkv = x @ W_qkv  (fp16 out), 256x256 tiles
    gemm_f16<_Float16, 256><<<dim3(C3 / 256, Mpad / 256), 512, 0, stream>>>(
        xh, WqkvT, nullptr, qkvh, Mrows, C3, Cc);

    // 2) attention
    col_attn<<<dim3(Ws, NHh, B_), 64, 0, stream>>>(qkvh, Ocol, mcol, lcol);
    cls_part<<<dim3(NHh, B_, 4), 1024, 0, stream>>>(qkvh, clsP);
    cls_merge<<<dim3(NHh, B_), 64, 0, stream>>>(clsP, attH);
    row_attn_merge<<<dim3(Hs, NHh, B_), 64, 0, stream>>>(qkvh, Ocol, mcol, lcol, attH);

    // 3) out = attH @ W_proj + b_proj  (fp32 out), 128x256 tiles (tail fix)
    gemm_f16<float, 128><<<dim3(Cc / 256, Mpad / 128), 512, 0, stream>>>(
        attH, WprojT, bproj, out, Mrows, Cc, Cc);
}

// Round 5
// 678.127 us; speedup vs baseline: 1.2133x; 1.2133x over previous
//
#include <hip/hip_runtime.h>
#include <math.h>

#define B_   8
#define Hs   56
#define Ws   56
#define Cc   768
#define NHh  12
#define HDd  64
#define Nt   3137
#define HW_  3136
#define C3   2304
#define SCALE 0.125f
#define Mrows (B_ * Nt)        // 25096
#define Mpad  (99 * 256)       // 25344 (multiple of 256 and 128)

typedef _Float16 half8  __attribute__((ext_vector_type(8)));
typedef _Float16 half4  __attribute__((ext_vector_type(4)));
typedef _Float16 half2_ __attribute__((ext_vector_type(2)));
typedef float floatx4 __attribute__((ext_vector_type(4)));

#define WAITV(N) asm volatile("s_waitcnt vmcnt(" #N ")" ::: "memory")
#define WAITL    asm volatile("s_waitcnt lgkmcnt(0)" ::: "memory")

__device__ __forceinline__ void barrier_mem() {
    asm volatile("" ::: "memory");
    __builtin_amdgcn_s_barrier();
    asm volatile("" ::: "memory");
}

__device__ inline float fdot2f(half2_ a, half2_ b, float c) {
#if __has_builtin(__builtin_amdgcn_fdot2)
    return __builtin_amdgcn_fdot2(a, b, c, false);
#else
    return fmaf((float)a.x, (float)b.x, fmaf((float)a.y, (float)b.y, c));
#endif
}

__device__ __forceinline__ void gload_lds16(const _Float16* g, _Float16* l) {
    __builtin_amdgcn_global_load_lds(
        (const __attribute__((address_space(1))) void*)g,
        (__attribute__((address_space(3))) void*)l, 16, 0, 0);
}

// ---------------- scratch (__device__ globals) -----------------------------
__device__ _Float16 g_qkvh[(size_t)Mrows * C3];          // fp16 qkv (115 MB)
__device__ float    g_Ocol[(size_t)B_ * NHh * HW_ * HDd];
__device__ float    g_mcol[(size_t)B_ * NHh * HW_];
__device__ float    g_lcol[(size_t)B_ * NHh * HW_];
__device__ _Float16 g_xh[(size_t)Mpad * Cc];
__device__ _Float16 g_attH[(size_t)Mpad * Cc];
__device__ _Float16 g_WqkvT[(size_t)C3 * Cc];
__device__ _Float16 g_WprojT[(size_t)Cc * Cc];
__device__ float    g_clsP[(size_t)B_ * NHh * 4 * 66];   // per-partial: m,l,O[64]

// ---------------- fp32 -> fp16 convert -------------------------------------
__global__ __launch_bounds__(256) void cvt_f16(
    const float* __restrict__ in, _Float16* __restrict__ out, int n4)
{
    for (int i = blockIdx.x * 256 + threadIdx.x; i < n4; i += gridDim.x * 256) {
        float4 v = ((const float4*)in)[i];
        half4 h = { (_Float16)v.x, (_Float16)v.y, (_Float16)v.z, (_Float16)v.w };
        ((half4*)out)[i] = h;
    }
}

// ---------------- fp32 [R][Cq] -> fp16 transposed [Cq][R] ------------------
__global__ __launch_bounds__(256) void transpose_f16(
    const float* __restrict__ in, _Float16* __restrict__ out, int R, int Cq)
{
    __shared__ float t[32][33];
    const int c0 = blockIdx.x * 32, r0 = blockIdx.y * 32;
    const int tx = threadIdx.x & 31, ty = threadIdx.x >> 5;
#pragma unroll
    for (int i = 0; i < 32; i += 8)
        t[ty + i][tx] = in[(size_t)(r0 + ty + i) * Cq + c0 + tx];
    __syncthreads();
#pragma unroll
    for (int i = 0; i < 32; i += 8)
        out[(size_t)(c0 + ty + i) * R + r0 + tx] = (_Float16)t[tx][ty + i];
}

// ---------------------------------------------------------------------------
// fp16 MFMA GEMM: C[M,Nd] = A[Mpad,K] @ Bt[Nd,K]^T (+bias).
// 8-phase schedule (T3+T4+T5), BMx256 tile, BK=64, 512 thr (8 waves 2Mx4N).
// Two LDS dbufs; per K-tile 4 phases, counted vmcnt once per tile (never 0
// in steady state). Epilogue: LDS bounce -> coalesced 16B/lane stores.
// ---------------------------------------------------------------------------
template <typename OutT, int BM>
__global__ __launch_bounds__(512, 2) void gemm_f16(
    const _Float16* __restrict__ A, const _Float16* __restrict__ Bt,
    const float* __restrict__ bias, OutT* __restrict__ Cm,
    int M, int Nd, int K)
{
    constexpr int MI   = BM / 32;        // acc rows per wave (8 or 4)
    constexpr int MIH  = MI / 2;
    constexpr int LA   = BM / 128;       // loads/thread per A half-tile (2 or 1)
    constexpr int ASZh = BM * 64;        // halfs per A K-tile buffer
    constexpr int BSZh = 256 * 64;       // halfs per B K-tile buffer
    constexpr size_t MAINB = (size_t)2 * (ASZh + BSZh) * 2;
    constexpr size_t EPIB  = sizeof(OutT) == 2 ? (size_t)BM * 280 * 2
                                               : (size_t)BM * 140 * 4;
    constexpr size_t SMEMB = MAINB > EPIB ? MAINB : EPIB;
    __shared__ __align__(16) char smem[SMEMB];

    const int tid = threadIdx.x;
    const int wave = tid >> 6, lane = tid & 63;
    const int wm = wave & 1, wn = wave >> 1;

    // panel swizzle: 16 row-blocks per panel, col-major within panel
    const int bid = blockIdx.y * gridDim.x + blockIdx.x;
    const int perPanel = gridDim.x * 16;
    const int panel = bid / perPanel;
    const int rowsIn = min(16, (int)gridDim.y - panel * 16);
    const int rem = bid - panel * perPanel;
    const int by = panel * 16 + rem % rowsIn;
    const int bx = rem / rowsIn;
    const int mBase = by * BM, nBase = bx * 256;

    const int rU  = ((tid >> 7) << 4) + (tid & 15);
    const int kcU = (tid >> 4) & 7;

    auto stageHalf = [&](int kt, int h) {
        _Float16* arena = (_Float16*)smem + (size_t)(kt & 1) * (ASZh + BSZh);
        if (h < 2) {
            _Float16* ldsA = arena + h * (ASZh / 2) + tid * 8;
            const _Float16* g = A + (size_t)(mBase + h * (BM / 2) + rU) * K
                                  + kt * 64 + kcU * 8;
#pragma unroll
            for (int j = 0; j < LA; ++j)
                gload_lds16(g + (size_t)j * 64 * K, ldsA + j * 4096);
        } else {
            const int hh = h - 2;
            _Float16* ldsB = arena + ASZh + hh * (BSZh / 2) + tid * 8;
            const _Float16* g = Bt + (size_t)(nBase + hh * 128 + rU) * K
                                   + kt * 64 + kcU * 8;
#pragma unroll
            for (int j = 0; j < 2; ++j)
                gload_lds16(g + (size_t)j * 64 * K, ldsB + j * 4096);
        }
    };

    const int fo = (lane >> 4) * 128 + (lane & 15) * 8;

    floatx4 acc[MI][4] = {};
    half8 a[MIH], b[4];

    const int NT = K >> 6;               // 12 K-tiles of 64
    stageHalf(0, 0); stageHalf(0, 1); stageHalf(0, 2); stageHalf(0, 3);

    for (int t = 0; t < NT; ++t) {
        const _Float16* aA = (const _Float16*)smem
                             + (size_t)(t & 1) * (ASZh + BSZh);
        const _Float16* aB = aA + ASZh;
        const bool st = (t + 1 < NT);

        // ---- q0: kk=0, mi-lo ----
        if (st) stageHalf(t + 1, 0);
        if (!st) { WAITV(0); }
        else if constexpr (LA == 2) { WAITV(2); }
        else { WAITV(1); }
        barrier_mem();
#pragma unroll
        for (int ni = 0; ni < 4; ++ni)
            b[ni] = *(const half8*)&aB[(wn * 4 + ni) * 1024 + fo];
#pragma unroll
        for (int mi = 0; mi < MIH; ++mi)
            a[mi] = *(const half8*)&aA[(wm * MI + mi) * 1024 + fo];
        WAITL;
        __builtin_amdgcn_s_setprio(1);
#pragma unroll
        for (int mi = 0; mi < MIH; ++mi)
#pragma unroll
            for (int ni = 0; ni < 4; ++ni)
                acc[mi][ni] = __builtin_amdgcn_mfma_f32_16x16x32_f16(
                    b[ni], a[mi], acc[mi][ni], 0, 0, 0);
        __builtin_amdgcn_s_setprio(0);
        barrier_mem();

        // ---- q1: kk=0, mi-hi ----
        if (st) stageHalf(t + 1, 1);
#pragma unroll
        for (int mi = 0; mi < MIH; ++mi)
            a[mi] = *(const half8*)&aA[(wm * MI + MIH + mi) * 1024 + fo];
        WAITL;
        __builtin_amdgcn_s_setprio(1);
#pragma unroll
        for (int mi = 0; mi < MIH; ++mi)
#pragma unroll
            for (int ni = 0; ni < 4; ++ni)
                acc[MIH + mi][ni] = __builtin_amdgcn_mfma_f32_16x16x32_f16(
                    b[ni], a[mi], acc[MIH + mi][ni], 0, 0, 0);
        __builtin_amdgcn_s_setprio(0);
        barrier_mem();

        // ---- q2: kk=1, mi-lo ----
        if (st) stageHalf(t + 1, 2);
#pragma unroll
        for (int ni = 0; ni < 4; ++ni)
            b[ni] = *(const half8*)&aB[(wn * 4 + ni) * 1024 + 512 + fo];
#pragma unroll
        for (int mi = 0; mi < MIH; ++mi)
            a[mi] = *(const half8*)&aA[(wm * MI + mi) * 1024 + 512 + fo];
        WAITL;
        __builtin_amdgcn_s_setprio(1);
#pragma unroll
        for (int mi = 0; mi < MIH; ++mi)
#pragma unroll
            for (int ni = 0; ni < 4; ++ni)
                acc[mi][ni] = __builtin_amdgcn_mfma_f32_16x16x32_f16(
                    b[ni], a[mi], acc[mi][ni], 0, 0, 0);
        __builtin_amdgcn_s_setprio(0);
        barrier_mem();

        // ---- q3: kk=1, mi-hi ----
        if (st) stageHalf(t + 1, 3);
#pragma unroll
        for (int mi = 0; mi < MIH; ++mi)
            a[mi] = *(const half8*)&aA[(wm * MI + MIH + mi) * 1024 + 512 + fo];
        WAITL;
        __builtin_amdgcn_s_setprio(1);
#pragma unroll
        for (int mi = 0; mi < MIH; ++mi)
#pragma unroll
            for (int ni = 0; ni < 4; ++ni)
                acc[MIH + mi][ni] = __builtin_amdgcn_mfma_f32_16x16x32_f16(
                    b[ni], a[mi], acc[MIH + mi][ni], 0, 0, 0);
        __builtin_amdgcn_s_setprio(0);
        barrier_mem();     // end of tile: all reads of dbuf(t) drained
    }

    // -------- epilogue: LDS bounce --------
    const int mlBase = wm * (BM / 2) + (lane & 15);
    const int nlBase = wn * 64 + ((lane >> 4) << 2);

    if constexpr (sizeof(OutT) == 2) {
        _Float16* Ch = (_Float16*)smem;          // [BM][280] halfs
#pragma unroll
        for (int ni = 0; ni < 4; ++ni) {
            const int nl = nlBase + ni * 16;
#pragma unroll
            for (int mi = 0; mi < MI; ++mi) {
                const int ml = mlBase + mi * 16;
                floatx4 v = acc[mi][ni];
                half4 h = { (_Float16)v[0], (_Float16)v[1],
                            (_Float16)v[2], (_Float16)v[3] };
                *(half4*)&Ch[ml * 280 + nl] = h;
            }
        }
        barrier_mem();
#pragma unroll
        for (int i = 0; i < BM / 16; ++i) {
            const int f = i * 512 + tid;
            const int row = f >> 5, u = f & 31;
            const int gm = mBase + row;
            if (gm < M)
                *(half8*)&Cm[(size_t)gm * Nd + nBase + u * 8] =
                    *(const half8*)&Ch[row * 280 + u * 8];
        }
    } else {
        float* Cf = (float*)smem;                // [BM][140] floats
#pragma unroll
        for (int nh = 0; nh < 2; ++nh) {
            barrier_mem();                       // prev pass reads done
            if ((wn >> 1) == nh) {
#pragma unroll
                for (int ni = 0; ni < 4; ++ni) {
                    const int n0 = nBase + wn * 64 + ((lane >> 4) << 2) + ni * 16;
                    float4 bv = bias ? *(const float4*)&bias[n0]
                                     : make_float4(0.f, 0.f, 0.f, 0.f);
                    const int nl = (wn & 1) * 64 + ((lane >> 4) << 2) + ni * 16;
#pragma unroll
                    for (int mi = 0; mi < MI; ++mi) {
                        const int ml = mlBase + mi * 16;
                        floatx4 v = acc[mi][ni];
                        float4 o = make_float4(v[0] + bv.x, v[1] + bv.y,
                                               v[2] + bv.z, v[3] + bv.w);
                        *(float4*)&Cf[ml * 140 + nl] = o;
                    }
                }
            }
            barrier_mem();
#pragma unroll
            for (int i = 0; i < BM / 16; ++i) {
                const int f = i * 512 + tid;
                const int row = f >> 5, u = f & 31;
                const int gm = mBase + row;
                if (gm < M)
                    *(float4*)&Cm[(size_t)gm * Nd + nBase + nh * 128 + u * 4] =
                        *(const float4*)&Cf[row * 140 + u * 4];
            }
        }
    }
}

// ---------------------------------------------------------------------------
// Column attention partials: block (w,nh,b), 64 thr. R5: per-key online
// softmax (R3 structure, VGPR ~88) + fp16 V in LDS (14.3 KB -> 11 blocks/CU).
// PV inner uses p*(float)vh via v_fma_mix. Unnormalized partial out (fp32).
// ---------------------------------------------------------------------------
__global__ __launch_bounds__(64) void col_attn(
    const _Float16* __restrict__ qkvh, float* __restrict__ Ocol,
    float* __restrict__ mcol, float* __restrict__ lcol)
{
    const int w = blockIdx.x, nh = blockIdx.y, b = blockIdx.z;
    __shared__ __align__(16) _Float16 Kh[57 * HDd];
    __shared__ __align__(16) _Float16 Vh[57 * HDd];
    const int tid = threadIdx.x;

    for (int e = tid; e < 57 * 8; e += 64) {
        int j = e >> 3, c = e & 7;
        int n = (j == 0) ? 0 : ((j - 1) * Ws + w + 1);
        const _Float16* base = qkvh + (size_t)(b * Nt + n) * C3 + nh * HDd + c * 8;
        *(half8*)&Kh[j * HDd + c * 8] = *(const half8*)(base + Cc);
        *(half8*)&Vh[j * HDd + c * 8] = *(const half8*)(base + 2 * Cc);
    }
    __syncthreads();

    if (tid < Hs) {
        const int h = tid;
        const int n = h * Ws + w + 1;
        const _Float16* qp = qkvh + (size_t)(b * Nt + n) * C3 + nh * HDd;
        half8 q8[8];
#pragma unroll
        for (int c = 0; c < 8; ++c) q8[c] = ((const half8*)qp)[c];

        float m = -INFINITY, l = 0.f;
        float4 O4[16] = {};

        for (int j = 0; j <= Hs; ++j) {
            const half8* kp = (const half8*)&Kh[j * HDd];
            float s0 = 0.f, s1 = 0.f, s2 = 0.f, s3 = 0.f;
#pragma unroll
            for (int c = 0; c < 8; ++c) {
                half8 kk = kp[c];
                const half2_* k2 = (const half2_*)&kk;
                const half2_* qq = (const half2_*)&q8[c];
                s0 = fdot2f(qq[0], k2[0], s0);
                s1 = fdot2f(qq[1], k2[1], s1);
                s2 = fdot2f(qq[2], k2[2], s2);
                s3 = fdot2f(qq[3], k2[3], s3);
            }
            float s = ((s0 + s1) + (s2 + s3)) * SCALE;
            float mn = fmaxf(m, s);
            float corr = __expf(m - mn);
            float p = __expf(s - mn);
            l = l * corr + p;
            const half8* vp = (const half8*)&Vh[j * HDd];
#pragma unroll
            for (int d8 = 0; d8 < 8; ++d8) {
                half8 vv = vp[d8];
                float4* o0 = &O4[d8 * 2];
                float4* o1 = &O4[d8 * 2 + 1];
                o0->x = fmaf(o0->x, corr, p * (float)vv[0]);
                o0->y = fmaf(o0->y, corr, p * (float)vv[1]);
                o0->z = fmaf(o0->z, corr, p * (float)vv[2]);
                o0->w = fmaf(o0->w, corr, p * (float)vv[3]);
                o1->x = fmaf(o1->x, corr, p * (float)vv[4]);
                o1->y = fmaf(o1->y, corr, p * (float)vv[5]);
                o1->z = fmaf(o1->z, corr, p * (float)vv[6]);
                o1->w = fmaf(o1->w, corr, p * (float)vv[7]);
            }
            m = mn;
        }
        const size_t qi = (size_t)((b * NHh + nh) * HW_ + h * Ws + w);
        mcol[qi] = m;
        lcol[qi] = l;
#pragma unroll
        for (int d4 = 0; d4 < 16; ++d4)
            *(float4*)&Ocol[qi * HDd + d4 * 4] = O4[d4];
    }
}

// ---------------------------------------------------------------------------
// Row attention + merge -> attH (fp16). R5: per-key online softmax (R3
// structure) + fp16 V in LDS.
// ---------------------------------------------------------------------------
__global__ __launch_bounds__(64) void row_attn_merge(
    const _Float16* __restrict__ qkvh, const float* __restrict__ Ocol,
    const float* __restrict__ mcol, const float* __restrict__ lcol,
    _Float16* __restrict__ attH)
{
    const int h = blockIdx.x, nh = blockIdx.y, b = blockIdx.z;
    __shared__ __align__(16) _Float16 Kh[Ws * HDd];
    __shared__ __align__(16) _Float16 Vh[Ws * HDd];
    const int tid = threadIdx.x;

    for (int e = tid; e < Ws * 8; e += 64) {
        int j = e >> 3, c = e & 7;
        int n = h * Ws + j + 1;
        const _Float16* base = qkvh + (size_t)(b * Nt + n) * C3 + nh * HDd + c * 8;
        *(half8*)&Kh[j * HDd + c * 8] = *(const half8*)(base + Cc);
        *(half8*)&Vh[j * HDd + c * 8] = *(const half8*)(base + 2 * Cc);
    }
    __syncthreads();

    if (tid < Ws) {
        const int w = tid;
        const int n = h * Ws + w + 1;
        const _Float16* qp = qkvh + (size_t)(b * Nt + n) * C3 + nh * HDd;
        half8 q8[8];
#pragma unroll
        for (int c = 0; c < 8; ++c) q8[c] = ((const half8*)qp)[c];

        float m = -INFINITY, l = 0.f;
        float4 O4[16] = {};

        for (int j = 0; j < Ws; ++j) {
            if (j == w) continue;
            const half8* kp = (const half8*)&Kh[j * HDd];
            float s0 = 0.f, s1 = 0.f, s2 = 0.f, s3 = 0.f;
#pragma unroll
            for (int c = 0; c < 8; ++c) {
                half8 kk = kp[c];
                const half2_* k2 = (const half2_*)&kk;
                const half2_* qq = (const half2_*)&q8[c];
                s0 = fdot2f(qq[0], k2[0], s0);
                s1 = fdot2f(qq[1], k2[1], s1);
                s2 = fdot2f(qq[2], k2[2], s2);
                s3 = fdot2f(qq[3], k2[3], s3);
            }
            float s = ((s0 + s1) + (s2 + s3)) * SCALE;
            float mn = fmaxf(m, s);
            float corr = __expf(m - mn);
            float p = __expf(s - mn);
            l = l * corr + p;
            const half8* vp = (const half8*)&Vh[j * HDd];
#pragma unroll
            for (int d8 = 0; d8 < 8; ++d8) {
                half8 vv = vp[d8];
                float4* o0 = &O4[d8 * 2];
                float4* o1 = &O4[d8 * 2 + 1];
                o0->x = fmaf(o0->x, corr, p * (float)vv[0]);
                o0->y = fmaf(o0->y, corr, p * (float)vv[1]);
                o0->z = fmaf(o0->z, corr, p * (float)vv[2]);
                o0->w = fmaf(o0->w, corr, p * (float)vv[3]);
                o1->x = fmaf(o1->x, corr, p * (float)vv[4]);
                o1->y = fmaf(o1->y, corr, p * (float)vv[5]);
                o1->z = fmaf(o1->z, corr, p * (float)vv[6]);
                o1->w = fmaf(o1->w, corr, p * (float)vv[7]);
            }
            m = mn;
        }

        const size_t qi = (size_t)((b * NHh + nh) * HW_ + h * Ws + w);
        const float mc = mcol[qi], lc = lcol[qi];
        const float mn = fmaxf(mc, m);
        const float fc = __expf(mc - mn);
        const float fr = __expf(m - mn);
        const float inv = 1.f / (lc * fc + l * fr);
        _Float16* op = attH + (size_t)(b * Nt + n) * Cc + nh * HDd;
        const float* ocp = Ocol + qi * HDd;
#pragma unroll
        for (int d4 = 0; d4 < 16; ++d4) {
            float4 oc = *(const float4*)(ocp + d4 * 4);
            half4 r = { (_Float16)((oc.x * fc + O4[d4].x * fr) * inv),
                        (_Float16)((oc.y * fc + O4[d4].y * fr) * inv),
                        (_Float16)((oc.z * fc + O4[d4].z * fr) * inv),
                        (_Float16)((oc.w * fc + O4[d4].w * fr) * inv) };
            *(half4*)(op + d4 * 4) = r;
        }
    }
}

// ---------------------------------------------------------------------------
// Cls-token attention, 4-way key-split for occupancy. Partial (m,l,O) per
// (b,nh,s); merged by cls_merge.
// ---------------------------------------------------------------------------
__global__ __launch_bounds__(1024) void cls_part(
    const _Float16* __restrict__ qkvh, float* __restrict__ P)
{
    const int nh = blockIdx.x, b = blockIdx.y, sidx = blockIdx.z;
    const int j0 = sidx * 785, j1 = min(Nt, j0 + 785);
    const int tid = threadIdx.x;
    const int lane = tid & 63, wv = tid >> 6;

    const float qd = (float)qkvh[(size_t)(b * Nt) * C3 + nh * HDd + lane];
    float m = -INFINITY, l = 0.f, Od = 0.f;

    for (int j = j0 + wv; j < j1; j += 16) {
        const _Float16* base = qkvh + (size_t)(b * Nt + j) * C3 + nh * HDd;
        float prod = qd * (float)base[Cc + lane];
#pragma unroll
        for (int off = 32; off >= 1; off >>= 1)
            prod += __shfl_xor(prod, off, 64);
        float s = prod * SCALE;
        float mn = fmaxf(m, s);
        float corr = __expf(m - mn);
        float p = __expf(s - mn);
        l = l * corr + p;
        Od = fmaf(Od, corr, p * (float)base[2 * Cc + lane]);
        m = mn;
    }

    __shared__ float sm[16], sl[16], sO[16][64];
    if (lane == 0) { sm[wv] = m; sl[wv] = l; }
    sO[wv][lane] = Od;
    __syncthreads();

    if (tid < 64) {
        float M2 = sm[0];
#pragma unroll
        for (int i = 1; i < 16; ++i) M2 = fmaxf(M2, sm[i]);
        float L = 0.f, OO = 0.f;
#pragma unroll
        for (int i = 0; i < 16; ++i) {
            float f = __expf(sm[i] - M2);
            L += sl[i] * f;
            OO += sO[i][tid] * f;
        }
        float* pp = P + (size_t)((b * NHh + nh) * 4 + sidx) * 66;
        if (tid == 0) { pp[0] = M2; pp[1] = L; }
        pp[2 + tid] = OO;
    }
}

__global__ __launch_bounds__(64) void cls_merge(
    const float* __restrict__ P, _Float16* __restrict__ attH)
{
    const int nh = blockIdx.x, b = blockIdx.y;
    const int tid = threadIdx.x;
    const float* p0 = P + (size_t)(b * NHh + nh) * 4 * 66;
    float M2 = fmaxf(fmaxf(p0[0], p0[66]), fmaxf(p0[132], p0[198]));
    float L = 0.f, OO = 0.f;
#pragma unroll
    for (int i = 0; i < 4; ++i) {
        const float* pp = p0 + i * 66;
        float f = __expf(pp[0] - M2);
        L += pp[1] * f;
        OO += pp[2 + tid] * f;
    }
    attH[(size_t)(b * Nt) * Cc + nh * HDd + tid] = (_Float16)(OO / L);
}

// ---------------------------------------------------------------------------
extern "C" void kernel_launch(void* const* d_in, const int* in_sizes, int n_in,
                              void* d_out, int out_size, void* d_ws, size_t ws_size,
                              hipStream_t stream)
{
    const float* x     = (const float*)d_in[0];
    const float* Wqkv  = (const float*)d_in[1];
    const float* Wproj = (const float*)d_in[2];
    const float* bproj = (const float*)d_in[3];
    float* out = (float*)d_out;

    _Float16* qkvh;   hipGetSymbolAddress((void**)&qkvh,   HIP_SYMBOL(g_qkvh));
    float*    Ocol;   hipGetSymbolAddress((void**)&Ocol,   HIP_SYMBOL(g_Ocol));
    float*    mcol;   hipGetSymbolAddress((void**)&mcol,   HIP_SYMBOL(g_mcol));
    float*    lcol;   hipGetSymbolAddress((void**)&lcol,   HIP_SYMBOL(g_lcol));
    _Float16* xh;     hipGetSymbolAddress((void**)&xh,     HIP_SYMBOL(g_xh));
    _Float16* attH;   hipGetSymbolAddress((void**)&attH,   HIP_SYMBOL(g_attH));
    _Float16* WqkvT;  hipGetSymbolAddress((void**)&WqkvT,  HIP_SYMBOL(g_WqkvT));
    _Float16* WprojT; hipGetSymbolAddress((void**)&WprojT, HIP_SYMBOL(g_WprojT));
    float*    clsP;   hipGetSymbolAddress((void**)&clsP,   HIP_SYMBOL(g_clsP));

    // 0) prep
    cvt_f16<<<4096, 256, 0, stream>>>(x, xh, (Mrows * Cc) / 4);
    transpose_f16<<<dim3(C3 / 32, Cc / 32), 256, 0, stream>>>(Wqkv, WqkvT, Cc, C3);
    transpose_f16<<<dim3(Cc / 32, Cc / 32), 256, 0, stream>>>(Wproj, WprojT, Cc, Cc);

    // 1) qkv = x @ W_qkv  (fp16 out), 256x256 tiles
    gemm_f16<_Float16, 256><<<dim3(C3 / 256, Mpad / 256), 512, 0, stream>>>(
        xh, WqkvT, nullptr, qkvh, Mrows, C3, Cc);

    // 2) attention
    col_attn<<<dim3(Ws, NHh, B_), 64, 0, stream>>>(qkvh, Ocol, mcol, lcol);
    cls_part<<<dim3(NHh, B_, 4), 1024, 0, stream>>>(qkvh, clsP);
    cls_merge<<<dim3(NHh, B_), 64, 0, stream>>>(clsP, attH);
    row_attn_merge<<<dim3(Hs, NHh, B_), 64, 0, stream>>>(qkvh, Ocol, mcol, lcol, attH);

    // 3) out = attH @ W_proj + b_proj  (fp32 out), 128x256 tiles (tail fix)
    gemm_f16<float, 128><<<dim3(Cc / 256, Mpad / 128), 512, 0, stream>>>(
        attH, WprojT, bproj, out, Mrows, Cc, Cc);
}

// Round 6
// 504.037 us; speedup vs baseline: 1.6323x; 1.3454x over previous
//
#include <hip/hip_runtime.h>
#include <math.h>

#define B_   8
#define Hs   56
#define Ws   56
#define Cc   768
#define NHh  12
#define HDd  64
#define Nt   3137
#define HW_  3136
#define C3   2304
#define SCALE 0.125f
#define Mrows (B_ * Nt)        // 25096
#define Mpad  (99 * 256)       // 25344 (multiple of 256 and 128)

typedef _Float16 half8  __attribute__((ext_vector_type(8)));
typedef _Float16 half4  __attribute__((ext_vector_type(4)));
typedef _Float16 half2_ __attribute__((ext_vector_type(2)));
typedef float floatx4 __attribute__((ext_vector_type(4)));

#define WAITV(N) asm volatile("s_waitcnt vmcnt(" #N ")" ::: "memory")
#define WAITL    asm volatile("s_waitcnt lgkmcnt(0)" ::: "memory")

__device__ __forceinline__ void barrier_mem() {
    asm volatile("" ::: "memory");
    __builtin_amdgcn_s_barrier();
    asm volatile("" ::: "memory");
}

__device__ __forceinline__ void gload_lds16(const _Float16* g, _Float16* l) {
    __builtin_amdgcn_global_load_lds(
        (const __attribute__((address_space(1))) void*)g,
        (__attribute__((address_space(3))) void*)l, 16, 0, 0);
}

// ---------------- scratch (__device__ globals) -----------------------------
__device__ _Float16 g_qkvh[(size_t)Mrows * C3];          // fp16 qkv (115 MB)
__device__ float    g_Ocol[(size_t)B_ * NHh * HW_ * HDd];
__device__ float    g_mcol[(size_t)B_ * NHh * HW_];
__device__ float    g_lcol[(size_t)B_ * NHh * HW_];
__device__ _Float16 g_xh[(size_t)Mpad * Cc];
__device__ _Float16 g_attH[(size_t)Mpad * Cc];
__device__ _Float16 g_WqkvT[(size_t)C3 * Cc];
__device__ _Float16 g_WprojT[(size_t)Cc * Cc];
__device__ float    g_clsP[(size_t)B_ * NHh * 4 * 66];   // per-partial: m,l,O[64]

// ---------------- fp32 -> fp16 convert -------------------------------------
__global__ __launch_bounds__(256) void cvt_f16(
    const float* __restrict__ in, _Float16* __restrict__ out, int n4)
{
    for (int i = blockIdx.x * 256 + threadIdx.x; i < n4; i += gridDim.x * 256) {
        float4 v = ((const float4*)in)[i];
        half4 h = { (_Float16)v.x, (_Float16)v.y, (_Float16)v.z, (_Float16)v.w };
        ((half4*)out)[i] = h;
    }
}

// ---------------- fp32 [R][Cq] -> fp16 transposed [Cq][R] ------------------
__global__ __launch_bounds__(256) void transpose_f16(
    const float* __restrict__ in, _Float16* __restrict__ out, int R, int Cq)
{
    __shared__ float t[32][33];
    const int c0 = blockIdx.x * 32, r0 = blockIdx.y * 32;
    const int tx = threadIdx.x & 31, ty = threadIdx.x >> 5;
#pragma unroll
    for (int i = 0; i < 32; i += 8)
        t[ty + i][tx] = in[(size_t)(r0 + ty + i) * Cq + c0 + tx];
    __syncthreads();
#pragma unroll
    for (int i = 0; i < 32; i += 8)
        out[(size_t)(c0 + ty + i) * R + r0 + tx] = (_Float16)t[tx][ty + i];
}

// ---------------------------------------------------------------------------
// fp16 MFMA GEMM: C[M,Nd] = A[Mpad,K] @ Bt[Nd,K]^T (+bias).
// 8-phase schedule (T3+T4+T5), BMx256 tile, BK=64, 512 thr (8 waves 2Mx4N).
// ---------------------------------------------------------------------------
template <typename OutT, int BM>
__global__ __launch_bounds__(512, 2) void gemm_f16(
    const _Float16* __restrict__ A, const _Float16* __restrict__ Bt,
    const float* __restrict__ bias, OutT* __restrict__ Cm,
    int M, int Nd, int K)
{
    constexpr int MI   = BM / 32;
    constexpr int MIH  = MI / 2;
    constexpr int LA   = BM / 128;
    constexpr int ASZh = BM * 64;
    constexpr int BSZh = 256 * 64;
    constexpr size_t MAINB = (size_t)2 * (ASZh + BSZh) * 2;
    constexpr size_t EPIB  = sizeof(OutT) == 2 ? (size_t)BM * 280 * 2
                                               : (size_t)BM * 140 * 4;
    constexpr size_t SMEMB = MAINB > EPIB ? MAINB : EPIB;
    __shared__ __align__(16) char smem[SMEMB];

    const int tid = threadIdx.x;
    const int wave = tid >> 6, lane = tid & 63;
    const int wm = wave & 1, wn = wave >> 1;

    const int bid = blockIdx.y * gridDim.x + blockIdx.x;
    const int perPanel = gridDim.x * 16;
    const int panel = bid / perPanel;
    const int rowsIn = min(16, (int)gridDim.y - panel * 16);
    const int rem = bid - panel * perPanel;
    const int by = panel * 16 + rem % rowsIn;
    const int bx = rem / rowsIn;
    const int mBase = by * BM, nBase = bx * 256;

    const int rU  = ((tid >> 7) << 4) + (tid & 15);
    const int kcU = (tid >> 4) & 7;

    auto stageHalf = [&](int kt, int h) {
        _Float16* arena = (_Float16*)smem + (size_t)(kt & 1) * (ASZh + BSZh);
        if (h < 2) {
            _Float16* ldsA = arena + h * (ASZh / 2) + tid * 8;
            const _Float16* g = A + (size_t)(mBase + h * (BM / 2) + rU) * K
                                  + kt * 64 + kcU * 8;
#pragma unroll
            for (int j = 0; j < LA; ++j)
                gload_lds16(g + (size_t)j * 64 * K, ldsA + j * 4096);
        } else {
            const int hh = h - 2;
            _Float16* ldsB = arena + ASZh + hh * (BSZh / 2) + tid * 8;
            const _Float16* g = Bt + (size_t)(nBase + hh * 128 + rU) * K
                                   + kt * 64 + kcU * 8;
#pragma unroll
            for (int j = 0; j < 2; ++j)
                gload_lds16(g + (size_t)j * 64 * K, ldsB + j * 4096);
        }
    };

    const int fo = (lane >> 4) * 128 + (lane & 15) * 8;

    floatx4 acc[MI][4] = {};
    half8 a[MIH], b[4];

    const int NT = K >> 6;
    stageHalf(0, 0); stageHalf(0, 1); stageHalf(0, 2); stageHalf(0, 3);

    for (int t = 0; t < NT; ++t) {
        const _Float16* aA = (const _Float16*)smem
                             + (size_t)(t & 1) * (ASZh + BSZh);
        const _Float16* aB = aA + ASZh;
        const bool st = (t + 1 < NT);

        // ---- q0 ----
        if (st) stageHalf(t + 1, 0);
        if (!st) { WAITV(0); }
        else if constexpr (LA == 2) { WAITV(2); }
        else { WAITV(1); }
        barrier_mem();
#pragma unroll
        for (int ni = 0; ni < 4; ++ni)
            b[ni] = *(const half8*)&aB[(wn * 4 + ni) * 1024 + fo];
#pragma unroll
        for (int mi = 0; mi < MIH; ++mi)
            a[mi] = *(const half8*)&aA[(wm * MI + mi) * 1024 + fo];
        WAITL;
        __builtin_amdgcn_s_setprio(1);
#pragma unroll
        for (int mi = 0; mi < MIH; ++mi)
#pragma unroll
            for (int ni = 0; ni < 4; ++ni)
                acc[mi][ni] = __builtin_amdgcn_mfma_f32_16x16x32_f16(
                    b[ni], a[mi], acc[mi][ni], 0, 0, 0);
        __builtin_amdgcn_s_setprio(0);
        barrier_mem();

        // ---- q1 ----
        if (st) stageHalf(t + 1, 1);
#pragma unroll
        for (int mi = 0; mi < MIH; ++mi)
            a[mi] = *(const half8*)&aA[(wm * MI + MIH + mi) * 1024 + fo];
        WAITL;
        __builtin_amdgcn_s_setprio(1);
#pragma unroll
        for (int mi = 0; mi < MIH; ++mi)
#pragma unroll
            for (int ni = 0; ni < 4; ++ni)
                acc[MIH + mi][ni] = __builtin_amdgcn_mfma_f32_16x16x32_f16(
                    b[ni], a[mi], acc[MIH + mi][ni], 0, 0, 0);
        __builtin_amdgcn_s_setprio(0);
        barrier_mem();

        // ---- q2 ----
        if (st) stageHalf(t + 1, 2);
#pragma unroll
        for (int ni = 0; ni < 4; ++ni)
            b[ni] = *(const half8*)&aB[(wn * 4 + ni) * 1024 + 512 + fo];
#pragma unroll
        for (int mi = 0; mi < MIH; ++mi)
            a[mi] = *(const half8*)&aA[(wm * MI + mi) * 1024 + 512 + fo];
        WAITL;
        __builtin_amdgcn_s_setprio(1);
#pragma unroll
        for (int mi = 0; mi < MIH; ++mi)
#pragma unroll
            for (int ni = 0; ni < 4; ++ni)
                acc[mi][ni] = __builtin_amdgcn_mfma_f32_16x16x32_f16(
                    b[ni], a[mi], acc[mi][ni], 0, 0, 0);
        __builtin_amdgcn_s_setprio(0);
        barrier_mem();

        // ---- q3 ----
        if (st) stageHalf(t + 1, 3);
#pragma unroll
        for (int mi = 0; mi < MIH; ++mi)
            a[mi] = *(const half8*)&aA[(wm * MI + MIH + mi) * 1024 + 512 + fo];
        WAITL;
        __builtin_amdgcn_s_setprio(1);
#pragma unroll
        for (int mi = 0; mi < MIH; ++mi)
#pragma unroll
            for (int ni = 0; ni < 4; ++ni)
                acc[MIH + mi][ni] = __builtin_amdgcn_mfma_f32_16x16x32_f16(
                    b[ni], a[mi], acc[MIH + mi][ni], 0, 0, 0);
        __builtin_amdgcn_s_setprio(0);
        barrier_mem();
    }

    // -------- epilogue: LDS bounce --------
    const int mlBase = wm * (BM / 2) + (lane & 15);
    const int nlBase = wn * 64 + ((lane >> 4) << 2);

    if constexpr (sizeof(OutT) == 2) {
        _Float16* Ch = (_Float16*)smem;          // [BM][280]
#pragma unroll
        for (int ni = 0; ni < 4; ++ni) {
            const int nl = nlBase + ni * 16;
#pragma unroll
            for (int mi = 0; mi < MI; ++mi) {
                const int ml = mlBase + mi * 16;
                floatx4 v = acc[mi][ni];
                half4 h = { (_Float16)v[0], (_Float16)v[1],
                            (_Float16)v[2], (_Float16)v[3] };
                *(half4*)&Ch[ml * 280 + nl] = h;
            }
        }
        barrier_mem();
#pragma unroll
        for (int i = 0; i < BM / 16; ++i) {
            const int f = i * 512 + tid;
            const int row = f >> 5, u = f & 31;
            const int gm = mBase + row;
            if (gm < M)
                *(half8*)&Cm[(size_t)gm * Nd + nBase + u * 8] =
                    *(const half8*)&Ch[row * 280 + u * 8];
        }
    } else {
        float* Cf = (float*)smem;                // [BM][140]
#pragma unroll
        for (int nh = 0; nh < 2; ++nh) {
            barrier_mem();
            if ((wn >> 1) == nh) {
#pragma unroll
                for (int ni = 0; ni < 4; ++ni) {
                    const int n0 = nBase + wn * 64 + ((lane >> 4) << 2) + ni * 16;
                    float4 bv = bias ? *(const float4*)&bias[n0]
                                     : make_float4(0.f, 0.f, 0.f, 0.f);
                    const int nl = (wn & 1) * 64 + ((lane >> 4) << 2) + ni * 16;
#pragma unroll
                    for (int mi = 0; mi < MI; ++mi) {
                        const int ml = mlBase + mi * 16;
                        floatx4 v = acc[mi][ni];
                        float4 o = make_float4(v[0] + bv.x, v[1] + bv.y,
                                               v[2] + bv.z, v[3] + bv.w);
                        *(float4*)&Cf[ml * 140 + nl] = o;
                    }
                }
            }
            barrier_mem();
#pragma unroll
            for (int i = 0; i < BM / 16; ++i) {
                const int f = i * 512 + tid;
                const int row = f >> 5, u = f & 31;
                const int gm = mBase + row;
                if (gm < M)
                    *(float4*)&Cm[(size_t)gm * Nd + nBase + nh * 128 + u * 4] =
                        *(const float4*)&Cf[row * 140 + u * 4];
            }
        }
    }
}

// ---------------------------------------------------------------------------
// R6: MFMA criss-cross attention. One wave per (x, nh, b); x = w (MODE 0,
// col: 57 keys incl cls) or h (MODE 1, row: 56 keys, diag mask, merges with
// col partials -> attH).
//  - S^T = mfma(Kfrag, Qfrag): lane holds 16 key-partials for one query col
//    -> in-lane softmax + 2 shfl_xor (cross-g).
//  - K/Q fragments loaded straight from global (no LDS).
//  - V^T staged to LDS with per-row rotate (j + 8*(d>>3))&63 (bank-safe both
//    directions); P bounced via [q][72] fp16 tile into Y-frag layout.
//  - O^T = mfma(Vtfrag, Pfrag); O bounced via [q][68] fp32 tile -> coalesced
//    per-lane 256B row stores.
// Fragment conventions verified by the GEMM above (harness-passed):
//   operands: row = lane&15, k = (lane>>4)*8+e;  output: i=(lane>>4)*4+r,
//   j = lane&15;  mfma(X,Y) => D[i][j] = sum_k X[i][k]*Y[j][k].
// ---------------------------------------------------------------------------
template <int MODE>
__global__ __launch_bounds__(64) void cc_attn(
    const _Float16* __restrict__ qkvh,
    float* __restrict__ Ocol, float* __restrict__ mcol,
    float* __restrict__ lcol, _Float16* __restrict__ attH)
{
    constexpr int NK = (MODE == 0) ? 57 : 56;
    const int x = blockIdx.x, nh = blockIdx.y, b = blockIdx.z;
    const int lane = threadIdx.x;
    const int q15 = lane & 15, g = lane >> 4;

    __shared__ __align__(16) char smem[18944];
    _Float16* Vt = (_Float16*)smem;                 // [64][72], rotated rows
    _Float16* Pl = (_Float16*)(smem + 9216);        // [64][72]
    float*    ML = (float*)(smem + 18432);          // [64] m, [64] l
    float*    Ol = (float*)smem;                    // [64][68] overlay

    const _Float16* base_b = qkvh + (size_t)(b * Nt) * C3 + nh * HDd;

    auto nrow_k = [&](int key) -> int {
        key = min(key, NK - 1);
        if (MODE == 0) return (key == 0) ? 0 : ((key - 1) * Ws + x + 1);
        return x * Ws + key + 1;
    };
    auto nrow_q = [&](int q) -> int {
        q = min(q, 55);
        return (MODE == 0) ? (q * Ws + x + 1) : (x * Ws + q + 1);
    };

    // ---- K/Q fragments from global (per-lane rows) ----
    half8 Kf[4][2], Qf[4][2];
#pragma unroll
    for (int t = 0; t < 4; ++t) {
        const _Float16* kp = base_b + (size_t)nrow_k(t * 16 + q15) * C3 + Cc;
        const _Float16* qp = base_b + (size_t)nrow_q(t * 16 + q15) * C3;
#pragma unroll
        for (int kk = 0; kk < 2; ++kk) {
            Kf[t][kk] = *(const half8*)(kp + kk * 32 + g * 8);
            Qf[t][kk] = *(const half8*)(qp + kk * 32 + g * 8);
        }
    }

    // ---- stage V^T into LDS (rotated, zero-padded keys >= NK) ----
#pragma unroll
    for (int it = 0; it < 8; ++it) {
        const int i = it * 64 + lane;
        const int j = i >> 3, c = i & 7;
        half8 v = {};
        if (j < NK)
            v = *(const half8*)(base_b + (size_t)nrow_k(j) * C3 + 2 * Cc + c * 8);
#pragma unroll
        for (int e = 0; e < 8; ++e)
            Vt[(c * 8 + e) * 72 + ((j + 8 * c) & 63)] = v[e];
    }

    // ---- S^T = K * Q^T ----
    floatx4 S[4][4] = {};   // [kt][qt]
#pragma unroll
    for (int kt = 0; kt < 4; ++kt)
#pragma unroll
        for (int qt = 0; qt < 4; ++qt)
#pragma unroll
            for (int kk = 0; kk < 2; ++kk)
                S[kt][qt] = __builtin_amdgcn_mfma_f32_16x16x32_f16(
                    Kf[kt][kk], Qf[qt][kk], S[kt][qt], 0, 0, 0);

    // ---- softmax per query column (in-lane 16 + cross-g shfl) ----
    float mq[4], lq[4];
#pragma unroll
    for (int qt = 0; qt < 4; ++qt) {
        const int q = qt * 16 + q15;
        float sv[4][4];
        float mm = -1e30f;
#pragma unroll
        for (int kt = 0; kt < 4; ++kt)
#pragma unroll
            for (int r = 0; r < 4; ++r) {
                const int key = kt * 16 + g * 4 + r;
                float s = S[kt][qt][r] * SCALE;
                const bool bad = (key >= NK) || (MODE == 1 && key == q);
                sv[kt][r] = bad ? -1e30f : s;
                mm = fmaxf(mm, sv[kt][r]);
            }
        mm = fmaxf(mm, __shfl_xor(mm, 16, 64));
        mm = fmaxf(mm, __shfl_xor(mm, 32, 64));
        float ll = 0.f;
#pragma unroll
        for (int kt = 0; kt < 4; ++kt) {
            half4 ph;
#pragma unroll
            for (int r = 0; r < 4; ++r) {
                const float p = __expf(sv[kt][r] - mm);
                ll += p;
                ph[r] = (_Float16)p;
            }
            *(half4*)&Pl[q * 72 + kt * 16 + g * 4] = ph;
        }
        ll += __shfl_xor(ll, 16, 64);
        ll += __shfl_xor(ll, 32, 64);
        mq[qt] = mm; lq[qt] = ll;
    }

    if (g == 0) {
        if (MODE == 0) {
#pragma unroll
            for (int qt = 0; qt < 4; ++qt) {
                const int q = qt * 16 + q15;
                if (q < 56) {
                    const size_t qi = (size_t)((b * NHh + nh) * HW_) + q * Ws + x;
                    mcol[qi] = mq[qt]; lcol[qi] = lq[qt];
                }
            }
        } else {
#pragma unroll
            for (int qt = 0; qt < 4; ++qt) {
                ML[qt * 16 + q15] = mq[qt];
                ML[64 + qt * 16 + q15] = lq[qt];
            }
        }
    }
    __syncthreads();

    // ---- O^T = V^T * P^T ----
    half8 Pf[4][2];
#pragma unroll
    for (int qt = 0; qt < 4; ++qt)
#pragma unroll
        for (int kk = 0; kk < 2; ++kk)
            Pf[qt][kk] = *(const half8*)&Pl[(qt * 16 + q15) * 72 + kk * 32 + g * 8];

    floatx4 O[4][4] = {};   // [dt][qt]
#pragma unroll
    for (int dt = 0; dt < 4; ++dt) {
        const int d = dt * 16 + q15;
        const int rot = 8 * (d >> 3);
        half8 Vf0 = *(const half8*)&Vt[d * 72 + ((0 + g * 8 + rot) & 63)];
        half8 Vf1 = *(const half8*)&Vt[d * 72 + ((32 + g * 8 + rot) & 63)];
#pragma unroll
        for (int qt = 0; qt < 4; ++qt) {
            O[dt][qt] = __builtin_amdgcn_mfma_f32_16x16x32_f16(
                Vf0, Pf[qt][0], O[dt][qt], 0, 0, 0);
            O[dt][qt] = __builtin_amdgcn_mfma_f32_16x16x32_f16(
                Vf1, Pf[qt][1], O[dt][qt], 0, 0, 0);
        }
    }
    __syncthreads();   // all Vt/Pl reads done before Ol overlay writes

    // ---- bounce O^T -> row-major rows in LDS ----
#pragma unroll
    for (int dt = 0; dt < 4; ++dt)
#pragma unroll
        for (int qt = 0; qt < 4; ++qt) {
            float4 f = { O[dt][qt][0], O[dt][qt][1], O[dt][qt][2], O[dt][qt][3] };
            *(float4*)&Ol[(qt * 16 + q15) * 68 + dt * 16 + g * 4] = f;
        }
    __syncthreads();

    // ---- per-lane row output ----
    const int qq = lane;
    if (qq < 56) {
        if (MODE == 0) {
            const size_t qi = (size_t)((b * NHh + nh) * HW_) + qq * Ws + x;
            float* op = Ocol + qi * HDd;
#pragma unroll
            for (int i = 0; i < 16; ++i)
                *(float4*)(op + i * 4) = *(const float4*)&Ol[qq * 68 + i * 4];
        } else {
            const size_t qi = (size_t)((b * NHh + nh) * HW_) + x * Ws + qq;
            const float mc = mcol[qi], lc = lcol[qi];
            const float mr = ML[qq], lr = ML[64 + qq];
            const float mn = fmaxf(mc, mr);
            const float fc = __expf(mc - mn);
            const float fr = __expf(mr - mn);
            const float inv = 1.f / (lc * fc + lr * fr);
            const int n = x * Ws + qq + 1;
            _Float16* op = attH + (size_t)(b * Nt + n) * Cc + nh * HDd;
            const float* ocp = Ocol + qi * HDd;
#pragma unroll
            for (int i = 0; i < 16; ++i) {
                float4 oc = *(const float4*)(ocp + i * 4);
                const float* oo = &Ol[qq * 68 + i * 4];
                half4 r = { (_Float16)((oc.x * fc + oo[0] * fr) * inv),
                            (_Float16)((oc.y * fc + oo[1] * fr) * inv),
                            (_Float16)((oc.z * fc + oo[2] * fr) * inv),
                            (_Float16)((oc.w * fc + oo[3] * fr) * inv) };
                *(half4*)(op + i * 4) = r;
            }
        }
    }
}

// ---------------------------------------------------------------------------
// Cls-token attention, 4-way key-split; merged by cls_merge.
// ---------------------------------------------------------------------------
__global__ __launch_bounds__(1024) void cls_part(
    const _Float16* __restrict__ qkvh, float* __restrict__ P)
{
    const int nh = blockIdx.x, b = blockIdx.y, sidx = blockIdx.z;
    const int j0 = sidx * 785, j1 = min(Nt, j0 + 785);
    const int tid = threadIdx.x;
    const int lane = tid & 63, wv = tid >> 6;

    const float qd = (float)qkvh[(size_t)(b * Nt) * C3 + nh * HDd + lane];
    float m = -INFINITY, l = 0.f, Od = 0.f;

    for (int j = j0 + wv; j < j1; j += 16) {
        const _Float16* base = qkvh + (size_t)(b * Nt + j) * C3 + nh * HDd;
        float prod = qd * (float)base[Cc + lane];
#pragma unroll
        for (int off = 32; off >= 1; off >>= 1)
            prod += __shfl_xor(prod, off, 64);
        float s = prod * SCALE;
        float mn = fmaxf(m, s);
        float corr = __expf(m - mn);
        float p = __expf(s - mn);
        l = l * corr + p;
        Od = fmaf(Od, corr, p * (float)base[2 * Cc + lane]);
        m = mn;
    }

    __shared__ float sm[16], sl[16], sO[16][64];
    if (lane == 0) { sm[wv] = m; sl[wv] = l; }
    sO[wv][lane] = Od;
    __syncthreads();

    if (tid < 64) {
        float M2 = sm[0];
#pragma unroll
        for (int i = 1; i < 16; ++i) M2 = fmaxf(M2, sm[i]);
        float L = 0.f, OO = 0.f;
#pragma unroll
        for (int i = 0; i < 16; ++i) {
            float f = __expf(sm[i] - M2);
            L += sl[i] * f;
            OO += sO[i][tid] * f;
        }
        float* pp = P + (size_t)((b * NHh + nh) * 4 + sidx) * 66;
        if (tid == 0) { pp[0] = M2; pp[1] = L; }
        pp[2 + tid] = OO;
    }
}

__global__ __launch_bounds__(64) void cls_merge(
    const float* __restrict__ P, _Float16* __restrict__ attH)
{
    const int nh = blockIdx.x, b = blockIdx.y;
    const int tid = threadIdx.x;
    const float* p0 = P + (size_t)(b * NHh + nh) * 4 * 66;
    float M2 = fmaxf(fmaxf(p0[0], p0[66]), fmaxf(p0[132], p0[198]));
    float L = 0.f, OO = 0.f;
#pragma unroll
    for (int i = 0; i < 4; ++i) {
        const float* pp = p0 + i * 66;
        float f = __expf(pp[0] - M2);
        L += pp[1] * f;
        OO += pp[2 + tid] * f;
    }
    attH[(size_t)(b * Nt) * Cc + nh * HDd + tid] = (_Float16)(OO / L);
}

// ---------------------------------------------------------------------------
extern "C" void kernel_launch(void* const* d_in, const int* in_sizes, int n_in,
                              void* d_out, int out_size, void* d_ws, size_t ws_size,
                              hipStream_t stream)
{
    const float* x     = (const float*)d_in[0];
    const float* Wqkv  = (const float*)d_in[1];
    const float* Wproj = (const float*)d_in[2];
    const float* bproj = (const float*)d_in[3];
    float* out = (float*)d_out;

    _Float16* qkvh;   hipGetSymbolAddress((void**)&qkvh,   HIP_SYMBOL(g_qkvh));
    float*    Ocol;   hipGetSymbolAddress((void**)&Ocol,   HIP_SYMBOL(g_Ocol));
    float*    mcol;   hipGetSymbolAddress((void**)&mcol,   HIP_SYMBOL(g_mcol));
    float*    lcol;   hipGetSymbolAddress((void**)&lcol,   HIP_SYMBOL(g_lcol));
    _Float16* xh;     hipGetSymbolAddress((void**)&xh,     HIP_SYMBOL(g_xh));
    _Float16* attH;   hipGetSymbolAddress((void**)&attH,   HIP_SYMBOL(g_attH));
    _Float16* WqkvT;  hipGetSymbolAddress((void**)&WqkvT,  HIP_SYMBOL(g_WqkvT));
    _Float16* WprojT; hipGetSymbolAddress((void**)&WprojT, HIP_SYMBOL(g_WprojT));
    float*    clsP;   hipGetSymbolAddress((void**)&clsP,   HIP_SYMBOL(g_clsP));

    // 0) prep
    cvt_f16<<<4096, 256, 0, stream>>>(x, xh, (Mrows * Cc) / 4);
    transpose_f16<<<dim3(C3 / 32, Cc / 32), 256, 0, stream>>>(Wqkv, WqkvT, Cc, C3);
    transpose_f16<<<dim3(Cc / 32, Cc / 32), 256, 0, stream>>>(Wproj, WprojT, Cc, Cc);

    // 1) qkv = x @ W_qkv  (fp16 out), 256x256 tiles
    gemm_f16<_Float16, 256><<<dim3(C3 / 256, Mpad / 256), 512, 0, stream>>>(
        xh, WqkvT, nullptr, qkvh, Mrows, C3, Cc);

    // 2) attention (MFMA)
    cc_attn<0><<<dim3(Ws, NHh, B_), 64, 0, stream>>>(qkvh, Ocol, mcol, lcol, attH);
    cls_part<<<dim3(NHh, B_, 4), 1024, 0, stream>>>(qkvh, clsP);
    cls_merge<<<dim3(NHh, B_), 64, 0, stream>>>(clsP, attH);
    cc_attn<1><<<dim3(Hs, NHh, B_), 64, 0, stream>>>(qkvh, Ocol, mcol, lcol, attH);

    // 3) out = attH @ W_proj + b_proj  (fp32 out), 128x256 tiles
    gemm_f16<float, 128><<<dim3(Cc / 256, Mpad / 128), 512, 0, stream>>>(
        attH, WprojT, bproj, out, Mrows, Cc, Cc);
}

// Round 7
// 482.700 us; speedup vs baseline: 1.7045x; 1.0442x over previous
//
#include <hip/hip_runtime.h>
#include <math.h>

#define B_   8
#define Hs   56
#define Ws   56
#define Cc   768
#define NHh  12
#define HDd  64
#define Nt   3137
#define HW_  3136
#define C3   2304
#define SCALE 0.125f
#define Mrows (B_ * Nt)        // 25096
#define Mpad  (99 * 256)       // 25344 (multiple of 256 and 128)

typedef _Float16 half8  __attribute__((ext_vector_type(8)));
typedef _Float16 half4  __attribute__((ext_vector_type(4)));
typedef _Float16 half2_ __attribute__((ext_vector_type(2)));
typedef float floatx4 __attribute__((ext_vector_type(4)));

#define WAITV(N) asm volatile("s_waitcnt vmcnt(" #N ")" ::: "memory")
#define WAITL    asm volatile("s_waitcnt lgkmcnt(0)" ::: "memory")

__device__ __forceinline__ void barrier_mem() {
    asm volatile("" ::: "memory");
    __builtin_amdgcn_s_barrier();
    asm volatile("" ::: "memory");
}

__device__ __forceinline__ void gload_lds16(const _Float16* g, _Float16* l) {
    __builtin_amdgcn_global_load_lds(
        (const __attribute__((address_space(1))) void*)g,
        (__attribute__((address_space(3))) void*)l, 16, 0, 0);
}

// ---------------- scratch (__device__ globals) -----------------------------
__device__ _Float16 g_qkvh[(size_t)Mrows * C3];          // fp16 qkv (115 MB)
__device__ float    g_Ocol[(size_t)B_ * NHh * HW_ * HDd];
__device__ float    g_mcol[(size_t)B_ * NHh * HW_];
__device__ float    g_lcol[(size_t)B_ * NHh * HW_];
__device__ _Float16 g_xh[(size_t)Mpad * Cc];
__device__ _Float16 g_attH[(size_t)Mpad * Cc];
__device__ _Float16 g_WqkvT[(size_t)C3 * Cc];
__device__ _Float16 g_WprojT[(size_t)Cc * Cc];
__device__ float    g_clsP[(size_t)B_ * NHh * 4 * 66];   // per-partial: m,l,O[64]

// ---------------- fp32 -> fp16 convert -------------------------------------
__global__ __launch_bounds__(256) void cvt_f16(
    const float* __restrict__ in, _Float16* __restrict__ out, int n4)
{
    for (int i = blockIdx.x * 256 + threadIdx.x; i < n4; i += gridDim.x * 256) {
        float4 v = ((const float4*)in)[i];
        half4 h = { (_Float16)v.x, (_Float16)v.y, (_Float16)v.z, (_Float16)v.w };
        ((half4*)out)[i] = h;
    }
}

// ---------------- fp32 [R][Cq] -> fp16 transposed [Cq][R] ------------------
__global__ __launch_bounds__(256) void transpose_f16(
    const float* __restrict__ in, _Float16* __restrict__ out, int R, int Cq)
{
    __shared__ float t[32][33];
    const int c0 = blockIdx.x * 32, r0 = blockIdx.y * 32;
    const int tx = threadIdx.x & 31, ty = threadIdx.x >> 5;
#pragma unroll
    for (int i = 0; i < 32; i += 8)
        t[ty + i][tx] = in[(size_t)(r0 + ty + i) * Cq + c0 + tx];
    __syncthreads();
#pragma unroll
    for (int i = 0; i < 32; i += 8)
        out[(size_t)(c0 + ty + i) * R + r0 + tx] = (_Float16)t[tx][ty + i];
}

// ---------------------------------------------------------------------------
// fp16 MFMA GEMM: C[M,Nd] = A[Mpad,K] @ Bt[Nd,K]^T (+bias).
// R7: register-double-buffered K-loop. BMx256 tile, BK=32, 512 thr (8 waves
// 2Mx4N). FOUR rotating LDS buffers, staging depth-3 with counted vmcnt
// (never 0 in steady state). Per K-tile t (ONE barrier):
//   vmcnt(LPT)  -> tiles t AND t+1 resident (per-wave), barrier -> all waves
//   stage(t+3)  -> into buf(t-1) (reads of it completed >=2 barriers ago)
//   MFMA x (MI*4) on regs X (loaded last tile)  ||  ds_read regs Y <- tile t+1
// The MFMA cluster has NO lgkm dependency: ds_reads drain behind it; the
// compiler's auto-wait for Y lands at tile t+1's first use. Ping-pong X/Y is
// statically indexed via 2x-unrolled loop (NT=24 even). MFMA order per
// accumulator identical to R6 -> bit-identical numerics.
// Epilogue: LDS bounce -> coalesced stores (unchanged).
// ---------------------------------------------------------------------------
template <typename OutT, int BM>
__global__ __launch_bounds__(512, 2) void gemm_f16(
    const _Float16* __restrict__ A, const _Float16* __restrict__ Bt,
    const float* __restrict__ bias, OutT* __restrict__ Cm,
    int M, int Nd, int K)
{
    constexpr int MI   = BM / 32;        // 16-row groups per wave (8 or 4)
    constexpr int LA   = BM / 128;       // A loads/thread per K-tile (2 or 1)
    constexpr int ASZh = BM * 32;        // halfs per A K-tile buffer
    constexpr int BSZh = 256 * 32;       // halfs per B K-tile buffer
    constexpr int BUFh = ASZh + BSZh;
    constexpr size_t MAINB = (size_t)4 * BUFh * 2;
    constexpr size_t EPIB  = sizeof(OutT) == 2 ? (size_t)BM * 280 * 2
                                               : (size_t)BM * 140 * 4;
    constexpr size_t SMEMB = MAINB > EPIB ? MAINB : EPIB;
    __shared__ __align__(16) char smem[SMEMB];

    const int tid = threadIdx.x;
    const int wave = tid >> 6, lane = tid & 63;
    const int wm = wave & 1, wn = wave >> 1;

    // panel swizzle: 16 row-blocks per panel, col-major within panel
    const int bid = blockIdx.y * gridDim.x + blockIdx.x;
    const int perPanel = gridDim.x * 16;
    const int panel = bid / perPanel;
    const int rowsIn = min(16, (int)gridDim.y - panel * 16);
    const int rem = bid - panel * perPanel;
    const int by = panel * 16 + rem % rowsIn;
    const int bx = rem / rowsIn;
    const int mBase = by * BM, nBase = bx * 256;

    // staging geometry (verified layout): unit u (16B) -> row ((u>>6)<<4)+(u&15),
    // kc=(u>>4)&3, LDS byte off u*16. Thread handles u = i*512 + tid.
    const int mU  = ((tid >> 6) << 4) + (tid & 15);
    const int kcU = (tid >> 4) & 3;
    const _Float16* ga = A  + (size_t)(mBase + mU) * K + kcU * 8;
    const _Float16* gb = Bt + (size_t)(nBase + mU) * K + kcU * 8;

    auto stage = [&](int t) {
        char* base = smem + (size_t)(t & 3) * (BUFh * 2);
        _Float16* lA = (_Float16*)base + wave * 512;
        _Float16* lB = (_Float16*)base + ASZh + wave * 512;
        const _Float16* gaK = ga + t * 32;
        const _Float16* gbK = gb + t * 32;
#pragma unroll
        for (int i = 0; i < LA; ++i)
            gload_lds16(gaK + (size_t)i * 128 * K, lA + i * 4096);
#pragma unroll
        for (int i = 0; i < 2; ++i)
            gload_lds16(gbK + (size_t)i * 128 * K, lB + i * 4096);
    };

    // fragment read: group g (16 rows x 32 k = 512 halfs); conflict-free b128
    const int fo = (lane >> 4) * 128 + (lane & 15) * 8;
    auto readFrags = [&](int t, half8 (&a)[MI], half8 (&b)[4]) {
        const _Float16* bufA = (const _Float16*)(smem + (size_t)(t & 3) * (BUFh * 2));
        const _Float16* bufB = bufA + ASZh;
#pragma unroll
        for (int mi = 0; mi < MI; ++mi)
            a[mi] = *(const half8*)&bufA[(wm * MI + mi) * 512 + fo];
#pragma unroll
        for (int ni = 0; ni < 4; ++ni)
            b[ni] = *(const half8*)&bufB[(wn * 4 + ni) * 512 + fo];
    };

    floatx4 acc[MI][4] = {};
    half8 aX[MI], bX[4], aY[MI], bY[4];

    const int NT = K >> 5;               // 24 K-tiles of 32 (even)
    stage(0); stage(1); stage(2);        // depth-3 prologue
    if constexpr (LA == 2) { WAITV(8); } else { WAITV(6); }   // tile 0 resident
    barrier_mem();
    readFrags(0, aX, bX);

    auto tileBody = [&](int t, half8 (&aC)[MI], half8 (&bC)[4],
                        half8 (&aN)[MI], half8 (&bN)[4]) {
        if (t <= NT - 3) {
            if constexpr (LA == 2) { WAITV(4); } else { WAITV(3); }
        } else {
            WAITV(0);
        }
        barrier_mem();                    // t and t+1 resident for ALL waves
        if (t + 3 < NT) stage(t + 3);     // into buf(t-1): free since t-2
        __builtin_amdgcn_s_setprio(1);
        if (t + 1 < NT) readFrags(t + 1, aN, bN);   // drains behind MFMAs
#pragma unroll
        for (int mi = 0; mi < MI; ++mi)
#pragma unroll
            for (int ni = 0; ni < 4; ++ni)
                acc[mi][ni] = __builtin_amdgcn_mfma_f32_16x16x32_f16(
                    bC[ni], aC[mi], acc[mi][ni], 0, 0, 0);
        __builtin_amdgcn_s_setprio(0);
    };

    for (int t = 0; t < NT; t += 2) {
        tileBody(t,     aX, bX, aY, bY);
        tileBody(t + 1, aY, bY, aX, bX);
    }
    WAITL;
    barrier_mem();                        // LDS free for epilogue reuse

    // -------- epilogue: LDS bounce --------
    const int mlBase = wm * (BM / 2) + (lane & 15);
    const int nlBase = wn * 64 + ((lane >> 4) << 2);

    if constexpr (sizeof(OutT) == 2) {
        _Float16* Ch = (_Float16*)smem;          // [BM][280]
#pragma unroll
        for (int ni = 0; ni < 4; ++ni) {
            const int nl = nlBase + ni * 16;
#pragma unroll
            for (int mi = 0; mi < MI; ++mi) {
                const int ml = mlBase + mi * 16;
                floatx4 v = acc[mi][ni];
                half4 h = { (_Float16)v[0], (_Float16)v[1],
                            (_Float16)v[2], (_Float16)v[3] };
                *(half4*)&Ch[ml * 280 + nl] = h;
            }
        }
        barrier_mem();
#pragma unroll
        for (int i = 0; i < BM / 16; ++i) {
            const int f = i * 512 + tid;
            const int row = f >> 5, u = f & 31;
            const int gm = mBase + row;
            if (gm < M)
                *(half8*)&Cm[(size_t)gm * Nd + nBase + u * 8] =
                    *(const half8*)&Ch[row * 280 + u * 8];
        }
    } else {
        float* Cf = (float*)smem;                // [BM][140]
#pragma unroll
        for (int nh = 0; nh < 2; ++nh) {
            barrier_mem();
            if ((wn >> 1) == nh) {
#pragma unroll
                for (int ni = 0; ni < 4; ++ni) {
                    const int n0 = nBase + wn * 64 + ((lane >> 4) << 2) + ni * 16;
                    float4 bv = bias ? *(const float4*)&bias[n0]
                                     : make_float4(0.f, 0.f, 0.f, 0.f);
                    const int nl = (wn & 1) * 64 + ((lane >> 4) << 2) + ni * 16;
#pragma unroll
                    for (int mi = 0; mi < MI; ++mi) {
                        const int ml = mlBase + mi * 16;
                        floatx4 v = acc[mi][ni];
                        float4 o = make_float4(v[0] + bv.x, v[1] + bv.y,
                                               v[2] + bv.z, v[3] + bv.w);
                        *(float4*)&Cf[ml * 140 + nl] = o;
                    }
                }
            }
            barrier_mem();
#pragma unroll
            for (int i = 0; i < BM / 16; ++i) {
                const int f = i * 512 + tid;
                const int row = f >> 5, u = f & 31;
                const int gm = mBase + row;
                if (gm < M)
                    *(float4*)&Cm[(size_t)gm * Nd + nBase + nh * 128 + u * 4] =
                        *(const float4*)&Cf[row * 140 + u * 4];
            }
        }
    }
}

// ---------------------------------------------------------------------------
// R6 MFMA criss-cross attention (unchanged). One wave per (x, nh, b).
// ---------------------------------------------------------------------------
template <int MODE>
__global__ __launch_bounds__(64) void cc_attn(
    const _Float16* __restrict__ qkvh,
    float* __restrict__ Ocol, float* __restrict__ mcol,
    float* __restrict__ lcol, _Float16* __restrict__ attH)
{
    constexpr int NK = (MODE == 0) ? 57 : 56;
    const int x = blockIdx.x, nh = blockIdx.y, b = blockIdx.z;
    const int lane = threadIdx.x;
    const int q15 = lane & 15, g = lane >> 4;

    __shared__ __align__(16) char smem[18944];
    _Float16* Vt = (_Float16*)smem;                 // [64][72], rotated rows
    _Float16* Pl = (_Float16*)(smem + 9216);        // [64][72]
    float*    ML = (float*)(smem + 18432);          // [64] m, [64] l
    float*    Ol = (float*)smem;                    // [64][68] overlay

    const _Float16* base_b = qkvh + (size_t)(b * Nt) * C3 + nh * HDd;

    auto nrow_k = [&](int key) -> int {
        key = min(key, NK - 1);
        if (MODE == 0) return (key == 0) ? 0 : ((key - 1) * Ws + x + 1);
        return x * Ws + key + 1;
    };
    auto nrow_q = [&](int q) -> int {
        q = min(q, 55);
        return (MODE == 0) ? (q * Ws + x + 1) : (x * Ws + q + 1);
    };

    // ---- K/Q fragments from global (per-lane rows) ----
    half8 Kf[4][2], Qf[4][2];
#pragma unroll
    for (int t = 0; t < 4; ++t) {
        const _Float16* kp = base_b + (size_t)nrow_k(t * 16 + q15) * C3 + Cc;
        const _Float16* qp = base_b + (size_t)nrow_q(t * 16 + q15) * C3;
#pragma unroll
        for (int kk = 0; kk < 2; ++kk) {
            Kf[t][kk] = *(const half8*)(kp + kk * 32 + g * 8);
            Qf[t][kk] = *(const half8*)(qp + kk * 32 + g * 8);
        }
    }

    // ---- stage V^T into LDS (rotated, zero-padded keys >= NK) ----
#pragma unroll
    for (int it = 0; it < 8; ++it) {
        const int i = it * 64 + lane;
        const int j = i >> 3, c = i & 7;
        half8 v = {};
        if (j < NK)
            v = *(const half8*)(base_b + (size_t)nrow_k(j) * C3 + 2 * Cc + c * 8);
#pragma unroll
        for (int e = 0; e < 8; ++e)
            Vt[(c * 8 + e) * 72 + ((j + 8 * c) & 63)] = v[e];
    }

    // ---- S^T = K * Q^T ----
    floatx4 S[4][4] = {};   // [kt][qt]
#pragma unroll
    for (int kt = 0; kt < 4; ++kt)
#pragma unroll
        for (int qt = 0; qt < 4; ++qt)
#pragma unroll
            for (int kk = 0; kk < 2; ++kk)
                S[kt][qt] = __builtin_amdgcn_mfma_f32_16x16x32_f16(
                    Kf[kt][kk], Qf[qt][kk], S[kt][qt], 0, 0, 0);

    // ---- softmax per query column (in-lane 16 + cross-g shfl) ----
    float mq[4], lq[4];
#pragma unroll
    for (int qt = 0; qt < 4; ++qt) {
        const int q = qt * 16 + q15;
        float sv[4][4];
        float mm = -1e30f;
#pragma unroll
        for (int kt = 0; kt < 4; ++kt)
#pragma unroll
            for (int r = 0; r < 4; ++r) {
                const int key = kt * 16 + g * 4 + r;
                float s = S[kt][qt][r] * SCALE;
                const bool bad = (key >= NK) || (MODE == 1 && key == q);
                sv[kt][r] = bad ? -1e30f : s;
                mm = fmaxf(mm, sv[kt][r]);
            }
        mm = fmaxf(mm, __shfl_xor(mm, 16, 64));
        mm = fmaxf(mm, __shfl_xor(mm, 32, 64));
        float ll = 0.f;
#pragma unroll
        for (int kt = 0; kt < 4; ++kt) {
            half4 ph;
#pragma unroll
            for (int r = 0; r < 4; ++r) {
                const float p = __expf(sv[kt][r] - mm);
                ll += p;
                ph[r] = (_Float16)p;
            }
            *(half4*)&Pl[q * 72 + kt * 16 + g * 4] = ph;
        }
        ll += __shfl_xor(ll, 16, 64);
        ll += __shfl_xor(ll, 32, 64);
        mq[qt] = mm; lq[qt] = ll;
    }

    if (g == 0) {
        if (MODE == 0) {
#pragma unroll
            for (int qt = 0; qt < 4; ++qt) {
                const int q = qt * 16 + q15;
                if (q < 56) {
                    const size_t qi = (size_t)((b * NHh + nh) * HW_) + q * Ws + x;
                    mcol[qi] = mq[qt]; lcol[qi] = lq[qt];
                }
            }
        } else {
#pragma unroll
            for (int qt = 0; qt < 4; ++qt) {
                ML[qt * 16 + q15] = mq[qt];
                ML[64 + qt * 16 + q15] = lq[qt];
            }
        }
    }
    __syncthreads();

    // ---- O^T = V^T * P^T ----
    half8 Pf[4][2];
#pragma unroll
    for (int qt = 0; qt < 4; ++qt)
#pragma unroll
        for (int kk = 0; kk < 2; ++kk)
            Pf[qt][kk] = *(const half8*)&Pl[(qt * 16 + q15) * 72 + kk * 32 + g * 8];

    floatx4 O[4][4] = {};   // [dt][qt]
#pragma unroll
    for (int dt = 0; dt < 4; ++dt) {
        const int d = dt * 16 + q15;
        const int rot = 8 * (d >> 3);
        half8 Vf0 = *(const half8*)&Vt[d * 72 + ((0 + g * 8 + rot) & 63)];
        half8 Vf1 = *(const half8*)&Vt[d * 72 + ((32 + g * 8 + rot) & 63)];
#pragma unroll
        for (int qt = 0; qt < 4; ++qt) {
            O[dt][qt] = __builtin_amdgcn_mfma_f32_16x16x32_f16(
                Vf0, Pf[qt][0], O[dt][qt], 0, 0, 0);
            O[dt][qt] = __builtin_amdgcn_mfma_f32_16x16x32_f16(
                Vf1, Pf[qt][1], O[dt][qt], 0, 0, 0);
        }
    }
    __syncthreads();   // all Vt/Pl reads done before Ol overlay writes

    // ---- bounce O^T -> row-major rows in LDS ----
#pragma unroll
    for (int dt = 0; dt < 4; ++dt)
#pragma unroll
        for (int qt = 0; qt < 4; ++qt) {
            float4 f = { O[dt][qt][0], O[dt][qt][1], O[dt][qt][2], O[dt][qt][3] };
            *(float4*)&Ol[(qt * 16 + q15) * 68 + dt * 16 + g * 4] = f;
        }
    __syncthreads();

    // ---- per-lane row output ----
    const int qq = lane;
    if (qq < 56) {
        if (MODE == 0) {
            const size_t qi = (size_t)((b * NHh + nh) * HW_) + qq * Ws + x;
            float* op = Ocol + qi * HDd;
#pragma unroll
            for (int i = 0; i < 16; ++i)
                *(float4*)(op + i * 4) = *(const float4*)&Ol[qq * 68 + i * 4];
        } else {
            const size_t qi = (size_t)((b * NHh + nh) * HW_) + x * Ws + qq;
            const float mc = mcol[qi], lc = lcol[qi];
            const float mr = ML[qq], lr = ML[64 + qq];
            const float mn = fmaxf(mc, mr);
            const float fc = __expf(mc - mn);
            const float fr = __expf(mr - mn);
            const float inv = 1.f / (lc * fc + lr * fr);
            const int n = x * Ws + qq + 1;
            _Float16* op = attH + (size_t)(b * Nt + n) * Cc + nh * HDd;
            const float* ocp = Ocol + qi * HDd;
#pragma unroll
            for (int i = 0; i < 16; ++i) {
                float4 oc = *(const float4*)(ocp + i * 4);
                const float* oo = &Ol[qq * 68 + i * 4];
                half4 r = { (_Float16)((oc.x * fc + oo[0] * fr) * inv),
                            (_Float16)((oc.y * fc + oo[1] * fr) * inv),
                            (_Float16)((oc.z * fc + oo[2] * fr) * inv),
                            (_Float16)((oc.w * fc + oo[3] * fr) * inv) };
                *(half4*)(op + i * 4) = r;
            }
        }
    }
}

// ---------------------------------------------------------------------------
// Cls-token attention, 4-way key-split; merged by cls_merge.
// ---------------------------------------------------------------------------
__global__ __launch_bounds__(1024) void cls_part(
    const _Float16* __restrict__ qkvh, float* __restrict__ P)
{
    const int nh = blockIdx.x, b = blockIdx.y, sidx = blockIdx.z;
    const int j0 = sidx * 785, j1 = min(Nt, j0 + 785);
    const int tid = threadIdx.x;
    const int lane = tid & 63, wv = tid >> 6;

    const float qd = (float)qkvh[(size_t)(b * Nt) * C3 + nh * HDd + lane];
    float m = -INFINITY, l = 0.f, Od = 0.f;

    for (int j = j0 + wv; j < j1; j += 16) {
        const _Float16* base = qkvh + (size_t)(b * Nt + j) * C3 + nh * HDd;
        float prod = qd * (float)base[Cc + lane];
#pragma unroll
        for (int off = 32; off >= 1; off >>= 1)
            prod += __shfl_xor(prod, off, 64);
        float s = prod * SCALE;
        float mn = fmaxf(m, s);
        float corr = __expf(m - mn);
        float p = __expf(s - mn);
        l = l * corr + p;
        Od = fmaf(Od, corr, p * (float)base[2 * Cc + lane]);
        m = mn;
    }

    __shared__ float sm[16], sl[16], sO[16][64];
    if (lane == 0) { sm[wv] = m; sl[wv] = l; }
    sO[wv][lane] = Od;
    __syncthreads();

    if (tid < 64) {
        float M2 = sm[0];
#pragma unroll
        for (int i = 1; i < 16; ++i) M2 = fmaxf(M2, sm[i]);
        float L = 0.f, OO = 0.f;
#pragma unroll
        for (int i = 0; i < 16; ++i) {
            float f = __expf(sm[i] - M2);
            L += sl[i] * f;
            OO += sO[i][tid] * f;
        }
        float* pp = P + (size_t)((b * NHh + nh) * 4 + sidx) * 66;
        if (tid == 0) { pp[0] = M2; pp[1] = L; }
        pp[2 + tid] = OO;
    }
}

__global__ __launch_bounds__(64) void cls_merge(
    const float* __restrict__ P, _Float16* __restrict__ attH)
{
    const int nh = blockIdx.x, b = blockIdx.y;
    const int tid = threadIdx.x;
    const float* p0 = P + (size_t)(b * NHh + nh) * 4 * 66;
    float M2 = fmaxf(fmaxf(p0[0], p0[66]), fmaxf(p0[132], p0[198]));
    float L = 0.f, OO = 0.f;
#pragma unroll
    for (int i = 0; i < 4; ++i) {
        const float* pp = p0 + i * 66;
        float f = __expf(pp[0] - M2);
        L += pp[1] * f;
        OO += pp[2 + tid] * f;
    }
    attH[(size_t)(b * Nt) * Cc + nh * HDd + tid] = (_Float16)(OO / L);
}

// ---------------------------------------------------------------------------
extern "C" void kernel_launch(void* const* d_in, const int* in_sizes, int n_in,
                              void* d_out, int out_size, void* d_ws, size_t ws_size,
                              hipStream_t stream)
{
    const float* x     = (const float*)d_in[0];
    const float* Wqkv  = (const float*)d_in[1];
    const float* Wproj = (const float*)d_in[2];
    const float* bproj = (const float*)d_in[3];
    float* out = (float*)d_out;

    _Float16* qkvh;   hipGetSymbolAddress((void**)&qkvh,   HIP_SYMBOL(g_qkvh));
    float*    Ocol;   hipGetSymbolAddress((void**)&Ocol,   HIP_SYMBOL(g_Ocol));
    float*    mcol;   hipGetSymbolAddress((void**)&mcol,   HIP_SYMBOL(g_mcol));
    float*    lcol;   hipGetSymbolAddress((void**)&lcol,   HIP_SYMBOL(g_lcol));
    _Float16* xh;     hipGetSymbolAddress((void**)&xh,     HIP_SYMBOL(g_xh));
    _Float16* attH;   hipGetSymbolAddress((void**)&attH,   HIP_SYMBOL(g_attH));
    _Float16* WqkvT;  hipGetSymbolAddress((void**)&WqkvT,  HIP_SYMBOL(g_WqkvT));
    _Float16* WprojT; hipGetSymbolAddress((void**)&WprojT, HIP_SYMBOL(g_WprojT));
    float*    clsP;   hipGetSymbolAddress((void**)&clsP,   HIP_SYMBOL(g_clsP));

    // 0) prep
    cvt_f16<<<4096, 256, 0, stream>>>(x, xh, (Mrows * Cc) / 4);
    transpose_f16<<<dim3(C3 / 32, Cc / 32), 256, 0, stream>>>(Wqkv, WqkvT, Cc, C3);
    transpose_f16<<<dim3(Cc / 32, Cc / 32), 256, 0, stream>>>(Wproj, WprojT, Cc, Cc);

    // 1) qkv = x @ W_qkv  (fp16 out), 256x256 tiles
    gemm_f16<_Float16, 256><<<dim3(C3 / 256, Mpad / 256), 512, 0, stream>>>(
        xh, WqkvT, nullptr, qkvh, Mrows, C3, Cc);

    // 2) attention (MFMA)
    cc_attn<0><<<dim3(Ws, NHh, B_), 64, 0, stream>>>(qkvh, Ocol, mcol, lcol, attH);
    cls_part<<<dim3(NHh, B_, 4), 1024, 0, stream>>>(qkvh, clsP);
    cls_merge<<<dim3(NHh, B_), 64, 0, stream>>>(clsP, attH);
    cc_attn<1><<<dim3(Hs, NHh, B_), 64, 0, stream>>>(qkvh, Ocol, mcol, lcol, attH);

    // 3) out = attH @ W_proj + b_proj  (fp32 out), 128x256 tiles
    gemm_f16<float, 128><<<dim3(Cc / 256, Mpad / 128), 512, 0, stream>>>(
        attH, WprojT, bproj, out, Mrows, Cc, Cc);
}